// Round 2
// baseline (984.546 us; speedup 1.0000x reference)
//
#include <hip/hip_runtime.h>

#define EPS 1e-7f

static inline int cdiv_i(int a, int b) { return (a + b - 1) / b; }

__device__ __forceinline__ float eweight(float m) {
    return expf(fminf(fmaxf(-m, -20.0f), 20.0f));
}

// ---------------------------------------------------------------------------
// Exact factor-2 bilinear+antialias downsample (jax.image.resize semantics)
// ---------------------------------------------------------------------------
__global__ void downsample2_kernel(const float* __restrict__ in, float* __restrict__ out,
                                   int NC, int Hin, int Win, float scale) {
    const int Hout = Hin >> 1, Wout = Win >> 1;
    const int HWo = Hout * Wout;
    int idx = blockIdx.x * blockDim.x + threadIdx.x;
    if (idx >= NC * HWo) return;
    int nc = idx / HWo;
    int p = idx - nc * HWo;
    int i = p / Wout;
    int j = p - i * Wout;

    const float kk[4] = { 0.25f, 0.75f, 0.75f, 0.25f };
    float wy[4], wx[4], sy = 0.0f, sx = 0.0f;
    int r0 = 2 * i - 1, c0 = 2 * j - 1;
#pragma unroll
    for (int a = 0; a < 4; ++a) {
        int ra = r0 + a;
        wy[a] = (ra >= 0 && ra < Hin) ? kk[a] : 0.0f;
        sy += wy[a];
        int cb = c0 + a;
        wx[a] = (cb >= 0 && cb < Win) ? kk[a] : 0.0f;
        sx += wx[a];
    }
#pragma unroll
    for (int a = 0; a < 4; ++a) { wy[a] /= sy; wx[a] /= sx; }

    const float* base = in + (size_t)nc * Hin * Win;
    float acc = 0.0f;
#pragma unroll
    for (int a = 0; a < 4; ++a) {
        int ra = r0 + a;
        if (ra < 0 || ra >= Hin) continue;
        const float* row = base + (size_t)ra * Win;
        float racc = 0.0f;
#pragma unroll
        for (int b = 0; b < 4; ++b) {
            int cb = c0 + b;
            if (cb < 0 || cb >= Win) continue;
            racc += wx[b] * row[cb];
        }
        acc += wy[a] * racc;
    }
    out[(size_t)nc * HWo + p] = acc * scale;
}

// ---------------------------------------------------------------------------
// Tile-privatized soft-splat.
// Block owns a T x T target tile; processes all sources in the R-dilated
// region; accumulates num/den/wsum in LDS via ds_add_f32; writes finished
// tiles with plain coalesced stores (NCHW). Contribution (s->t) is applied
// by owner(t) iff s is within owner's region; rare far-flow sources are
// appended to a record list and applied by splat_fixup with global atomics.
// CB = channels per LDS pass.
// ---------------------------------------------------------------------------
template <int C, int H, int W, int T, int R, int CB>
__global__ __launch_bounds__(256) void splat_tile(
        const float* __restrict__ feat, const float* __restrict__ flow, float flow_scale,
        const float* __restrict__ metric, float* __restrict__ num, float* __restrict__ dh,
        int* __restrict__ rec_cnt, unsigned* __restrict__ rec_list, int rec_cap) {
    constexpr int HW = H * W;
    constexpr int RW = T + 2 * R;        // region width
    constexpr int RS = RW * RW;          // region sources
    constexpr int K = (RS + 255) / 256;  // sources per thread
    constexpr int TS = T + 1;            // padded LDS row stride (odd -> bank-friendly)
    constexpr int LSZ = T * TS + T + 1;  // biased-index span
    constexpr int TT = T * T;
    constexpr int TILES_X = W / T;
    constexpr int TILES = (W / T) * (H / T);

    __shared__ float sden[LSZ];
    __shared__ float swsum[LSZ];
    __shared__ float snum[CB * LSZ];

    const int tid = threadIdx.x;
    const int n = blockIdx.x / TILES;
    const int tt = blockIdx.x - n * TILES;
    const int ty0 = (tt / TILES_X) * T;
    const int tx0 = (tt - (tt / TILES_X) * TILES_X) * T;

    for (int i = tid; i < LSZ; i += 256) { sden[i] = 0.f; swsum[i] = 0.f; }
    for (int i = tid; i < CB * LSZ; i += 256) snum[i] = 0.f;
    __syncthreads();

    // per-source params kept in registers (static indexing via full unroll)
    float ex0[K], ex1[K], fyv[K];
    int pack[K];   // bits 0..11: biased LDS offset b=(oy+1)*TS+(ox+1); bits 16..19: corner guards
    int sOff[K];   // source linear offset within plane (clamped-safe)

    const float* flowx = flow + (size_t)(n * 2 + 0) * HW;
    const float* flowy = flow + (size_t)(n * 2 + 1) * HW;
    const float* met = metric + (size_t)n * HW;

#pragma unroll
    for (int k = 0; k < K; ++k) {
        pack[k] = 0; sOff[k] = 0; ex0[k] = 0.f; ex1[k] = 0.f; fyv[k] = 0.f;
        int r = tid + k * 256;
        if (r < RS) {
            int ry = r / RW;
            int rx = r - ry * RW;
            int sy = ty0 - R + ry;
            int sx = tx0 - R + rx;
            if ((unsigned)sx < (unsigned)W && (unsigned)sy < (unsigned)H) {
                int sp = sy * W + sx;
                sOff[k] = sp;
                float dx = flowx[sp] * flow_scale;
                float dy = flowy[sp] * flow_scale;
                float e = eweight(met[sp]);
                float gx = (float)sx + dx;
                float gy = (float)sy + dy;
                float x0f = floorf(gx), y0f = floorf(gy);
                float fx = gx - x0f, fy = gy - y0f;
                int x0 = (int)x0f, y0 = (int)y0f;
                int ox = x0 - tx0, oy = y0 - ty0;
                float wx0 = 1.f - fx, wx1 = fx, wy0 = 1.f - fy, wy1 = fy;
                bool vx0 = (unsigned)ox < (unsigned)T;
                bool vx1 = (unsigned)(ox + 1) < (unsigned)T;
                bool vy0 = (unsigned)oy < (unsigned)T;
                bool vy1 = (unsigned)(oy + 1) < (unsigned)T;
                int g = (vx0 && vy0 ? 1 << 16 : 0) | (vx1 && vy0 ? 1 << 17 : 0) |
                        (vx0 && vy1 ? 1 << 18 : 0) | (vx1 && vy1 ? 1 << 19 : 0);
                if (g) {
                    int bb = (oy + 1) * TS + (ox + 1);
                    pack[k] = g | bb;
                    if (g & (1 << 16)) { atomicAdd(&sden[bb - TS - 1], e * wx0 * wy0); atomicAdd(&swsum[bb - TS - 1], wx0 * wy0); }
                    if (g & (1 << 17)) { atomicAdd(&sden[bb - TS],     e * wx1 * wy0); atomicAdd(&swsum[bb - TS],     wx1 * wy0); }
                    if (g & (1 << 18)) { atomicAdd(&sden[bb - 1],      e * wx0 * wy1); atomicAdd(&swsum[bb - 1],      wx0 * wy1); }
                    if (g & (1 << 19)) { atomicAdd(&sden[bb],          e * wx1 * wy1); atomicAdd(&swsum[bb],          wx1 * wy1); }
                }
                ex0[k] = e * wx0; ex1[k] = e * wx1; fyv[k] = fy;

                // record emission: only the owner of s checks for far-flow misses
                bool owned = rx >= R && rx < R + T && ry >= R && ry < R + T;
                if (owned) {
                    int dxo = x0 - sx, dyo = y0 - sy;
                    // |t-s| <= R-1 in both axes => s is inside owner(t)'s region; no miss possible
                    if (dxo < -(R - 1) || dxo > R - 2 || dyo < -(R - 1) || dyo > R - 2) {
                        bool miss = false;
#pragma unroll
                        for (int ci = 0; ci < 2; ++ci)
#pragma unroll
                            for (int cj = 0; cj < 2; ++cj) {
                                int cx = x0 + cj, cy = y0 + ci;
                                if ((unsigned)cx < (unsigned)W && (unsigned)cy < (unsigned)H) {
                                    int bx0 = (cx / T) * T, by0 = (cy / T) * T;
                                    if (sx < bx0 - R || sx >= bx0 + T + R ||
                                        sy < by0 - R || sy >= by0 + T + R) miss = true;
                                }
                            }
                        if (miss) {
                            int ridx = atomicAdd(rec_cnt, 1);
                            if (ridx < rec_cap) rec_list[ridx] = (unsigned)(n * HW + sp);
                        }
                    }
                }
            }
        }
    }
    __syncthreads();

    // den / wsum writeback (plain stores, float2 per pixel)
    for (int i = tid; i < TT; i += 256) {
        int row = i / T, col = i - row * T;
        size_t gp = ((size_t)n * H + ty0 + row) * W + tx0 + col;
        *(float2*)(dh + gp * 2) = make_float2(sden[row * TS + col], swsum[row * TS + col]);
    }

    // channel passes: accumulate CB channels in LDS, then plain-store the tile
    for (int cc = 0; cc < C; cc += CB) {
        float fv[CB][K];
#pragma unroll
        for (int u = 0; u < CB; ++u) {
            const float* fp = feat + ((size_t)n * C + cc + u) * HW;
#pragma unroll
            for (int k = 0; k < K; ++k) fv[u][k] = fp[sOff[k]];
        }
#pragma unroll
        for (int k = 0; k < K; ++k) {
            int pk = pack[k];
            if (pk) {
                int bb = pk & 0xFFF;
                float wy1 = fyv[k], wy0 = 1.f - wy1;
#pragma unroll
                for (int u = 0; u < CB; ++u) {
                    float* sn = snum + u * LSZ;
                    float f = fv[u][k];
                    if (pk & (1 << 16)) atomicAdd(&sn[bb - TS - 1], f * ex0[k] * wy0);
                    if (pk & (1 << 17)) atomicAdd(&sn[bb - TS],     f * ex1[k] * wy0);
                    if (pk & (1 << 18)) atomicAdd(&sn[bb - 1],      f * ex0[k] * wy1);
                    if (pk & (1 << 19)) atomicAdd(&sn[bb],          f * ex1[k] * wy1);
                }
            }
        }
        __syncthreads();
        for (int i = tid; i < CB * TT; i += 256) {
            int u = i / TT;
            int r2 = i - u * TT;
            int row = r2 / T, col = r2 - row * T;
            int a = u * LSZ + row * TS + col;
            num[((size_t)n * C + cc + u) * HW + (size_t)(ty0 + row) * W + tx0 + col] = snum[a];
            snum[a] = 0.f;
        }
        __syncthreads();
    }
}

// ---------------------------------------------------------------------------
// Apply the (rare) far-flow contributions with global atomics. Runs after
// splat_tile, before normalization. Grid-strided over the record list.
// ---------------------------------------------------------------------------
template <int C, int H, int W, int T, int R>
__global__ __launch_bounds__(128) void splat_fixup(
        const float* __restrict__ feat, const float* __restrict__ flow, float flow_scale,
        const float* __restrict__ metric, float* __restrict__ num, float* __restrict__ dh,
        const int* __restrict__ rec_cnt, const unsigned* __restrict__ rec_list, int rec_cap) {
    constexpr int HW = H * W;
    int cnt = *rec_cnt;
    if (cnt > rec_cap) cnt = rec_cap;
    for (int rec = blockIdx.x; rec < cnt; rec += gridDim.x) {
        unsigned q = rec_list[rec];
        int n = q / HW;
        int p = q - n * HW;
        int sy = p / W;
        int sx = p - sy * W;
        float dx = flow[(size_t)(n * 2 + 0) * HW + p] * flow_scale;
        float dy = flow[(size_t)(n * 2 + 1) * HW + p] * flow_scale;
        float e = eweight(metric[(size_t)n * HW + p]);
        float gx = (float)sx + dx, gy = (float)sy + dy;
        float x0f = floorf(gx), y0f = floorf(gy);
        float fx = gx - x0f, fy = gy - y0f;
        int x0 = (int)x0f, y0 = (int)y0f;
        float wxs[2] = { 1.f - fx, fx }, wys[2] = { 1.f - fy, fy };
#pragma unroll
        for (int ci = 0; ci < 2; ++ci)
#pragma unroll
            for (int cj = 0; cj < 2; ++cj) {
                int cx = x0 + cj, cy = y0 + ci;
                if ((unsigned)cx >= (unsigned)W || (unsigned)cy >= (unsigned)H) continue;
                int bx0 = (cx / T) * T, by0 = (cy / T) * T;
                bool miss = sx < bx0 - R || sx >= bx0 + T + R ||
                            sy < by0 - R || sy >= by0 + T + R;
                if (!miss) continue;  // already applied by owner block
                float w = wxs[cj] * wys[ci];
                for (int c = threadIdx.x; c < C; c += 128)
                    atomicAdd(&num[((size_t)n * C + c) * HW + (size_t)cy * W + cx],
                              feat[((size_t)n * C + c) * HW + p] * (e * w));
                if (threadIdx.x == 0) {
                    size_t tp = ((size_t)n * H + cy) * W + cx;
                    atomicAdd(&dh[tp * 2], e * w);
                    atomicAdd(&dh[tp * 2 + 1], w);
                }
            }
    }
}

// ---------------------------------------------------------------------------
// NCHW normalize + hole mask (c==0 lanes). float4-vectorized.
// ---------------------------------------------------------------------------
template <int C, int H, int W>
__global__ __launch_bounds__(256) void norm_nchw(const float* __restrict__ num,
                                                 const float* __restrict__ dh,
                                                 float* __restrict__ out,
                                                 float* __restrict__ hole) {
    constexpr int HW = H * W;
    constexpr int N = 4;
    int q4 = blockIdx.x * 256 + threadIdx.x;
    if (q4 >= N * C * HW / 4) return;
    int idx = q4 * 4;
    int per = C * HW;
    int n = idx / per;
    int rem = idx - n * per;
    int c = rem / HW;
    int p = rem - c * HW;
    float4 v = *(const float4*)(num + idx);
    const float2* dp = (const float2*)(dh + ((size_t)n * HW + p) * 2);
    float2 d0 = dp[0], d1 = dp[1], d2 = dp[2], d3 = dp[3];
    float4 o;
    o.x = v.x / (d0.x + EPS);
    o.y = v.y / (d1.x + EPS);
    o.z = v.z / (d2.x + EPS);
    o.w = v.w / (d3.x + EPS);
    *(float4*)(out + idx) = o;
    if (c == 0) {
        float4 hm;
        hm.x = (d0.y / (d0.y + EPS) <= 0.5f) ? 1.f : 0.f;
        hm.y = (d1.y / (d1.y + EPS) <= 0.5f) ? 1.f : 0.f;
        hm.z = (d2.y / (d2.y + EPS) <= 0.5f) ? 1.f : 0.f;
        hm.w = (d3.y / (d3.y + EPS) <= 0.5f) ? 1.f : 0.f;
        *(float4*)(hole + (size_t)n * HW + p) = hm;
    }
}

// ---------------------------------------------------------------------------
// Ft2 splat: channels {dx*e, dy*e, e, pad} packed CS=4, pair-merged. (kept)
// ---------------------------------------------------------------------------
template <int H, int W>
__global__ __launch_bounds__(256) void splat_flow(const float* __restrict__ flow, float flow_scale,
                                                  const float* __restrict__ metric,
                                                  float* __restrict__ num) {
    constexpr int HW = H * W;
    const int lane = threadIdx.x & 63;
    const int wid = blockIdx.x * 4 + (threadIdx.x >> 6);
    const int q0 = wid * 64;
    const int n = q0 / HW;
    const int p0 = q0 - n * HW;

    const int p = p0 + lane;
    int y = p / W;
    int x = p - y * W;
    float dx = flow[(size_t)(n * 2 + 0) * HW + p] * flow_scale;
    float dy = flow[(size_t)(n * 2 + 1) * HW + p] * flow_scale;
    float m = metric[(size_t)n * HW + p];
    float e = eweight(m);
    float dxe = dx * e, dye = dy * e;
    float gx = (float)x + dx;
    float gy = (float)y + dy;
    float x0f = floorf(gx), y0f = floorf(gy);
    float fx = gx - x0f, fy = gy - y0f;
    int x0 = (int)x0f, y0 = (int)y0f;

#pragma unroll 4
    for (int i = 0; i < 64; ++i) {
        float fxi = __shfl(fx, i);
        float fyi = __shfl(fy, i);
        float ei = __shfl(e, i);
        float dxei = __shfl(dxe, i);
        float dyei = __shfl(dye, i);
        int x0b = __shfl(x0, i);
        int y0b = __shfl(y0, i);

        if (lane < 16) {
            int row = lane >> 3, slot = lane & 7, crn = slot >> 2, ch = slot & 3;
            int yt = y0b + row;
            int xt = x0b + crn;
            if ((unsigned)xt < (unsigned)W && (unsigned)yt < (unsigned)H) {
                float wr = (crn ? fxi : 1.0f - fxi) * (row ? fyi : 1.0f - fyi);
                float v = (ch == 0) ? dxei : (ch == 1) ? dyei : (ch == 2) ? ei : 0.0f;
                atomicAdd(&num[(((long long)n * H + yt) * (long long)W + x0b) * 4 + slot], wr * v);
            }
        }
    }
}

__global__ __launch_bounds__(256) void norm_flow(const float* __restrict__ num,
                                                 float* __restrict__ out, int HW, int total) {
    int q = blockIdx.x * blockDim.x + threadIdx.x;
    if (q >= total) return;
    float4 v = ((const float4*)num)[q];
    int n = q / HW;
    int p = q - n * HW;
    float inv = -1.0f / (v.z + EPS);
    out[((size_t)n * 2 + 0) * HW + p] = v.x * inv;
    out[((size_t)n * 2 + 1) * HW + p] = v.y * inv;
}

// ---------------------------------------------------------------------------
extern "C" void kernel_launch(void* const* d_in, const int* in_sizes, int n_in,
                              void* d_out, int out_size, void* d_ws, size_t ws_size,
                              hipStream_t stream) {
    const float* x1_0 = (const float*)d_in[0];
    const float* x1_1 = (const float*)d_in[2];
    const float* x1_2 = (const float*)d_in[4];
    const float* m1t  = (const float*)d_in[6];
    const float* m2t  = (const float*)d_in[7];
    const float* F12  = (const float*)d_in[8];
    const float* F21  = (const float*)d_in[9];

    const int N = 4;
    const int H0 = 256, W0 = 448;
    const int H1 = 128, W1 = 224;
    const int H2 = 64,  W2 = 112;
    const int HW0 = H0 * W0, HW1 = H1 * W1, HW2 = H2 * W2;
    const int NHW0 = N * HW0, NHW1 = N * HW1, NHW2 = N * HW2;

    // d_out layout (floats), reference return order
    const size_t o0 = 0;
    const size_t o1 = o0 + (size_t)N * 32 * HW0;
    const size_t o2 = o1 + (size_t)N * 64 * HW1;
    const size_t o3 = o2 + (size_t)N * 96 * HW2;
    const size_t o4 = o3 + (size_t)NHW0;
    const size_t o5 = o4 + (size_t)NHW1;
    const size_t o6 = o5 + (size_t)NHW2;
    float* out = (float*)d_out;

    // ws layout: [numF (zeroed) | rec counters (zeroed) | rec lists | small | num/dh buffers]
    float* ws_f = (float*)d_ws;
    float* numF = ws_f;                                   // NHW0*4, zeroed
    int* cnts = (int*)(numF + (size_t)NHW0 * 4);          // 4 ints (3 used), zeroed
    unsigned* list0 = (unsigned*)(cnts + 4);              // 4096
    unsigned* list1 = list0 + 4096;                       // 512
    unsigned* list2 = list1 + 512;                        // 512
    float* flow1   = (float*)(list2 + 512);               // 2*NHW1
    float* metric1 = flow1 + (size_t)2 * NHW1;            // NHW1
    float* flow2   = metric1 + NHW1;                      // 2*NHW2
    float* metric2 = flow2 + (size_t)2 * NHW2;            // NHW2
    float* num0 = metric2 + NHW2;                         // N*32*HW0
    float* dh0  = num0 + (size_t)N * 32 * HW0;            // NHW0*2
    float* num1 = dh0 + (size_t)NHW0 * 2;                 // N*64*HW1
    float* dh1  = num1 + (size_t)N * 64 * HW1;            // NHW1*2
    float* num2 = dh1 + (size_t)NHW1 * 2;                 // N*96*HW2
    float* dh2  = num2 + (size_t)N * 96 * HW2;            // NHW2*2

    hipMemsetAsync(ws_f, 0, ((size_t)NHW0 * 4 + 4) * sizeof(float), stream);

    const int B = 256;

    // pyramid resizes (flow scale folded: F1t = 0.5*F12)
    downsample2_kernel<<<cdiv_i(N * 1 * HW1, B), B, 0, stream>>>(m1t, metric1, N, H0, W0, 1.0f);
    downsample2_kernel<<<cdiv_i(N * 2 * HW1, B), B, 0, stream>>>(F12, flow1, N * 2, H0, W0, 0.25f);
    downsample2_kernel<<<cdiv_i(N * 1 * HW2, B), B, 0, stream>>>(metric1, metric2, N, H1, W1, 1.0f);
    downsample2_kernel<<<cdiv_i(N * 2 * HW2, B), B, 0, stream>>>(flow1, flow2, N * 2, H1, W1, 0.5f);

    // privatized splats: 448 blocks each (4 imgs x 14 x 8 tiles)
    splat_tile<32, 256, 448, 32, 16, 2><<<448, 256, 0, stream>>>(
        x1_0, F12, 0.5f, m1t, num0, dh0, cnts + 0, list0, 4096);
    splat_tile<64, 128, 224, 16, 4, 4><<<448, 256, 0, stream>>>(
        x1_1, flow1, 1.0f, metric1, num1, dh1, cnts + 1, list1, 512);
    splat_tile<96, 64, 112, 8, 4, 8><<<448, 256, 0, stream>>>(
        x1_2, flow2, 1.0f, metric2, num2, dh2, cnts + 2, list2, 512);
    splat_flow<256, 448><<<NHW0 / 256, 256, 0, stream>>>(F21, 0.5f, m2t, numF);

    // rare far-flow fixups (before normalization)
    splat_fixup<32, 256, 448, 32, 16><<<64, 128, 0, stream>>>(
        x1_0, F12, 0.5f, m1t, num0, dh0, cnts + 0, list0, 4096);
    splat_fixup<64, 128, 224, 16, 4><<<64, 128, 0, stream>>>(
        x1_1, flow1, 1.0f, metric1, num1, dh1, cnts + 1, list1, 512);
    splat_fixup<96, 64, 112, 8, 4><<<64, 128, 0, stream>>>(
        x1_2, flow2, 1.0f, metric2, num2, dh2, cnts + 2, list2, 512);

    // normalize (NCHW, no transpose needed) + hole masks
    norm_nchw<32, 256, 448><<<cdiv_i(N * 32 * HW0 / 4, B), B, 0, stream>>>(num0, dh0, out + o0, out + o3);
    norm_nchw<64, 128, 224><<<cdiv_i(N * 64 * HW1 / 4, B), B, 0, stream>>>(num1, dh1, out + o1, out + o4);
    norm_nchw<96, 64, 112><<<cdiv_i(N * 96 * HW2 / 4, B), B, 0, stream>>>(num2, dh2, out + o2, out + o5);
    norm_flow<<<cdiv_i(NHW0, B), B, 0, stream>>>(numF, out + o6, HW0, NHW0);
}

// Round 3
// 945.147 us; speedup vs baseline: 1.0417x; 1.0417x over previous
//
#include <hip/hip_runtime.h>

#define EPS 1e-7f

static inline int cdiv_i(int a, int b) { return (a + b - 1) / b; }

__device__ __forceinline__ float eweight(float m) {
    return expf(fminf(fmaxf(-m, -20.0f), 20.0f));
}

// ---------------------------------------------------------------------------
// Exact factor-2 bilinear+antialias downsample (jax.image.resize semantics)
// ---------------------------------------------------------------------------
__global__ void downsample2_kernel(const float* __restrict__ in, float* __restrict__ out,
                                   int NC, int Hin, int Win, float scale) {
    const int Hout = Hin >> 1, Wout = Win >> 1;
    const int HWo = Hout * Wout;
    int idx = blockIdx.x * blockDim.x + threadIdx.x;
    if (idx >= NC * HWo) return;
    int nc = idx / HWo;
    int p = idx - nc * HWo;
    int i = p / Wout;
    int j = p - i * Wout;

    const float kk[4] = { 0.25f, 0.75f, 0.75f, 0.25f };
    float wy[4], wx[4], sy = 0.0f, sx = 0.0f;
    int r0 = 2 * i - 1, c0 = 2 * j - 1;
#pragma unroll
    for (int a = 0; a < 4; ++a) {
        int ra = r0 + a;
        wy[a] = (ra >= 0 && ra < Hin) ? kk[a] : 0.0f;
        sy += wy[a];
        int cb = c0 + a;
        wx[a] = (cb >= 0 && cb < Win) ? kk[a] : 0.0f;
        sx += wx[a];
    }
#pragma unroll
    for (int a = 0; a < 4; ++a) { wy[a] /= sy; wx[a] /= sx; }

    const float* base = in + (size_t)nc * Hin * Win;
    float acc = 0.0f;
#pragma unroll
    for (int a = 0; a < 4; ++a) {
        int ra = r0 + a;
        if (ra < 0 || ra >= Hin) continue;
        const float* row = base + (size_t)ra * Win;
        float racc = 0.0f;
#pragma unroll
        for (int b = 0; b < 4; ++b) {
            int cb = c0 + b;
            if (cb < 0 || cb >= Win) continue;
            racc += wx[b] * row[cb];
        }
        acc += wy[a] * racc;
    }
    out[(size_t)nc * HWo + p] = acc * scale;
}

// ---------------------------------------------------------------------------
// Tile-privatized soft-splat, channel-split across blocks.
// Grid = N * TILES * (GROUPS+1). Group g < GROUPS handles channels
// [g*CB, g*CB+CB) in ONE LDS pass; group GROUPS computes den/wsum and emits
// far-flow records. Geometry is recomputed per group (VALU is idle; flow/
// metric re-reads are L2-hits since a tile's groups are dispatch-adjacent).
// ---------------------------------------------------------------------------
template <int C, int H, int W, int T, int R, int CB, int THREADS>
__global__ __launch_bounds__(THREADS) void splat_tile2(
        const float* __restrict__ feat, const float* __restrict__ flow, float flow_scale,
        const float* __restrict__ metric, float* __restrict__ num, float* __restrict__ dh,
        int* __restrict__ rec_cnt, unsigned* __restrict__ rec_list, int rec_cap) {
    constexpr int HW = H * W;
    constexpr int RW = T + 2 * R;
    constexpr int RS = RW * RW;
    constexpr int K = RS / THREADS;
    static_assert(RS % THREADS == 0, "THREADS must divide region size");
    constexpr int TS = T + 1;            // padded LDS row stride
    constexpr int LSZ = T * TS + T + 1;
    constexpr int TT = T * T;
    constexpr int TILES_X = W / T;
    constexpr int TILES = (W / T) * (H / T);
    constexpr int GROUPS = C / CB;

    __shared__ float sacc[CB * LSZ];

    const int tid = threadIdx.x;
    int b = blockIdx.x;
    const int g = b % (GROUPS + 1);
    b /= (GROUPS + 1);
    const int n = b / TILES;
    const int tt = b - n * TILES;
    const int ty0 = (tt / TILES_X) * T;
    const int tx0 = (tt - (tt / TILES_X) * TILES_X) * T;
    const bool is_den = (g == GROUPS);

    {
        const int zn = (is_den ? 2 : CB) * LSZ;
        for (int i = tid; i < zn; i += THREADS) sacc[i] = 0.f;
    }
    __syncthreads();

    const float* flowx = flow + (size_t)(n * 2 + 0) * HW;
    const float* flowy = flow + (size_t)(n * 2 + 1) * HW;
    const float* met = metric + (size_t)n * HW;
    const float* fbase = feat + ((size_t)n * C + (size_t)(is_den ? 0 : g) * CB) * HW;

#pragma unroll
    for (int k = 0; k < K; ++k) {
        int r = tid + k * THREADS;
        int ry = r / RW;
        int rx = r - ry * RW;
        int sy = ty0 - R + ry;
        int sx = tx0 - R + rx;
        if ((unsigned)sx >= (unsigned)W || (unsigned)sy >= (unsigned)H) continue;
        int sp = sy * W + sx;
        float dx = flowx[sp] * flow_scale;
        float dy = flowy[sp] * flow_scale;
        float e = eweight(met[sp]);
        float gx = (float)sx + dx;
        float gy = (float)sy + dy;
        float x0f = floorf(gx), y0f = floorf(gy);
        float fx = gx - x0f, fy = gy - y0f;
        int x0 = (int)x0f, y0 = (int)y0f;
        int ox = x0 - tx0, oy = y0 - ty0;
        float wx0 = 1.f - fx, wx1 = fx, wy0 = 1.f - fy, wy1 = fy;
        bool vx0 = (unsigned)ox < (unsigned)T;
        bool vx1 = (unsigned)(ox + 1) < (unsigned)T;
        bool vy0 = (unsigned)oy < (unsigned)T;
        bool vy1 = (unsigned)(oy + 1) < (unsigned)T;
        int bb = (oy + 1) * TS + (ox + 1);

        if (!is_den) {
            if (!((vx0 || vx1) && (vy0 || vy1))) continue;
            float fv[CB];
#pragma unroll
            for (int u = 0; u < CB; ++u) fv[u] = fbase[(size_t)u * HW + sp];
            float w00 = e * wx0 * wy0, w10 = e * wx1 * wy0;
            float w01 = e * wx0 * wy1, w11 = e * wx1 * wy1;
#pragma unroll
            for (int u = 0; u < CB; ++u) {
                float* sn = sacc + u * LSZ;
                if (vx0 && vy0) atomicAdd(&sn[bb - TS - 1], fv[u] * w00);
                if (vx1 && vy0) atomicAdd(&sn[bb - TS],     fv[u] * w10);
                if (vx0 && vy1) atomicAdd(&sn[bb - 1],      fv[u] * w01);
                if (vx1 && vy1) atomicAdd(&sn[bb],          fv[u] * w11);
            }
        } else {
            if (vx0 && vy0) { atomicAdd(&sacc[bb - TS - 1], e * wx0 * wy0); atomicAdd(&sacc[LSZ + bb - TS - 1], wx0 * wy0); }
            if (vx1 && vy0) { atomicAdd(&sacc[bb - TS],     e * wx1 * wy0); atomicAdd(&sacc[LSZ + bb - TS],     wx1 * wy0); }
            if (vx0 && vy1) { atomicAdd(&sacc[bb - 1],      e * wx0 * wy1); atomicAdd(&sacc[LSZ + bb - 1],      wx0 * wy1); }
            if (vx1 && vy1) { atomicAdd(&sacc[bb],          e * wx1 * wy1); atomicAdd(&sacc[LSZ + bb],          wx1 * wy1); }

            // far-flow record emission: only by the owner tile of s
            bool owned = rx >= R && rx < R + T && ry >= R && ry < R + T;
            if (owned) {
                int dxo = x0 - sx, dyo = y0 - sy;
                if (dxo < -(R - 1) || dxo > R - 2 || dyo < -(R - 1) || dyo > R - 2) {
                    bool miss = false;
#pragma unroll
                    for (int ci = 0; ci < 2; ++ci)
#pragma unroll
                        for (int cj = 0; cj < 2; ++cj) {
                            int cx = x0 + cj, cy = y0 + ci;
                            if ((unsigned)cx < (unsigned)W && (unsigned)cy < (unsigned)H) {
                                int bx0 = (cx / T) * T, by0 = (cy / T) * T;
                                if (sx < bx0 - R || sx >= bx0 + T + R ||
                                    sy < by0 - R || sy >= by0 + T + R) miss = true;
                            }
                        }
                    if (miss) {
                        int ridx = atomicAdd(rec_cnt, 1);
                        if (ridx < rec_cap) rec_list[ridx] = (unsigned)(n * HW + sp);
                    }
                }
            }
        }
    }
    __syncthreads();

    if (is_den) {
        for (int i = tid; i < TT; i += THREADS) {
            int row = i / T, col = i - row * T;
            size_t gp = ((size_t)n * H + ty0 + row) * W + tx0 + col;
            int a = row * TS + col;
            *(float2*)(dh + gp * 2) = make_float2(sacc[a], sacc[LSZ + a]);
        }
    } else {
        for (int i = tid; i < CB * TT; i += THREADS) {
            int u = i / TT;
            int r2 = i - u * TT;
            int row = r2 / T, col = r2 - row * T;
            num[((size_t)n * C + (size_t)g * CB + u) * HW + (size_t)(ty0 + row) * W + tx0 + col] =
                sacc[u * LSZ + row * TS + col];
        }
    }
}

// ---------------------------------------------------------------------------
// Apply the rare far-flow contributions with global atomics, parallel over
// (corner, channel). Runs after splat_tile2, before normalization.
// ---------------------------------------------------------------------------
template <int C, int H, int W, int T, int R>
__global__ __launch_bounds__(128) void splat_fixup(
        const float* __restrict__ feat, const float* __restrict__ flow, float flow_scale,
        const float* __restrict__ metric, float* __restrict__ num, float* __restrict__ dh,
        const int* __restrict__ rec_cnt, const unsigned* __restrict__ rec_list, int rec_cap) {
    constexpr int HW = H * W;
    int cnt = *rec_cnt;
    if (cnt > rec_cap) cnt = rec_cap;
    for (int rec = blockIdx.x; rec < cnt; rec += gridDim.x) {
        unsigned q = rec_list[rec];
        int n = q / HW;
        int p = q - n * HW;
        int sy = p / W;
        int sx = p - sy * W;
        float dx = flow[(size_t)(n * 2 + 0) * HW + p] * flow_scale;
        float dy = flow[(size_t)(n * 2 + 1) * HW + p] * flow_scale;
        float e = eweight(metric[(size_t)n * HW + p]);
        float gx = (float)sx + dx, gy = (float)sy + dy;
        float x0f = floorf(gx), y0f = floorf(gy);
        float fx = gx - x0f, fy = gy - y0f;
        int x0 = (int)x0f, y0 = (int)y0f;
        float wxs[2] = { 1.f - fx, fx }, wys[2] = { 1.f - fy, fy };
        for (int idx = threadIdx.x; idx < 4 * C; idx += 128) {
            int corner = idx / C;
            int c = idx - corner * C;
            int ci = corner >> 1, cj = corner & 1;
            int cx = x0 + cj, cy = y0 + ci;
            if ((unsigned)cx >= (unsigned)W || (unsigned)cy >= (unsigned)H) continue;
            int bx0 = (cx / T) * T, by0 = (cy / T) * T;
            bool miss = sx < bx0 - R || sx >= bx0 + T + R ||
                        sy < by0 - R || sy >= by0 + T + R;
            if (!miss) continue;  // applied by owner block already
            float w = wxs[cj] * wys[ci];
            atomicAdd(&num[((size_t)n * C + c) * HW + (size_t)cy * W + cx],
                      feat[((size_t)n * C + c) * HW + p] * (e * w));
            if (c == 0) {
                size_t tp = ((size_t)n * H + cy) * W + cx;
                atomicAdd(&dh[tp * 2], e * w);
                atomicAdd(&dh[tp * 2 + 1], w);
            }
        }
    }
}

// ---------------------------------------------------------------------------
// NCHW normalize + hole mask (c==0 lanes). float4-vectorized.
// ---------------------------------------------------------------------------
template <int C, int H, int W>
__global__ __launch_bounds__(256) void norm_nchw(const float* __restrict__ num,
                                                 const float* __restrict__ dh,
                                                 float* __restrict__ out,
                                                 float* __restrict__ hole) {
    constexpr int HW = H * W;
    constexpr int N = 4;
    int q4 = blockIdx.x * 256 + threadIdx.x;
    if (q4 >= N * C * HW / 4) return;
    int idx = q4 * 4;
    int per = C * HW;
    int n = idx / per;
    int rem = idx - n * per;
    int c = rem / HW;
    int p = rem - c * HW;
    float4 v = *(const float4*)(num + idx);
    const float2* dp = (const float2*)(dh + ((size_t)n * HW + p) * 2);
    float2 d0 = dp[0], d1 = dp[1], d2 = dp[2], d3 = dp[3];
    float4 o;
    o.x = v.x / (d0.x + EPS);
    o.y = v.y / (d1.x + EPS);
    o.z = v.z / (d2.x + EPS);
    o.w = v.w / (d3.x + EPS);
    *(float4*)(out + idx) = o;
    if (c == 0) {
        float4 hm;
        hm.x = (d0.y / (d0.y + EPS) <= 0.5f) ? 1.f : 0.f;
        hm.y = (d1.y / (d1.y + EPS) <= 0.5f) ? 1.f : 0.f;
        hm.z = (d2.y / (d2.y + EPS) <= 0.5f) ? 1.f : 0.f;
        hm.w = (d3.y / (d3.y + EPS) <= 0.5f) ? 1.f : 0.f;
        *(float4*)(hole + (size_t)n * HW + p) = hm;
    }
}

// ---------------------------------------------------------------------------
// Ft2 splat: channels {dx*e, dy*e, e, pad} packed CS=4, pair-merged. (kept)
// ---------------------------------------------------------------------------
template <int H, int W>
__global__ __launch_bounds__(256) void splat_flow(const float* __restrict__ flow, float flow_scale,
                                                  const float* __restrict__ metric,
                                                  float* __restrict__ num) {
    constexpr int HW = H * W;
    const int lane = threadIdx.x & 63;
    const int wid = blockIdx.x * 4 + (threadIdx.x >> 6);
    const int q0 = wid * 64;
    const int n = q0 / HW;
    const int p0 = q0 - n * HW;

    const int p = p0 + lane;
    int y = p / W;
    int x = p - y * W;
    float dx = flow[(size_t)(n * 2 + 0) * HW + p] * flow_scale;
    float dy = flow[(size_t)(n * 2 + 1) * HW + p] * flow_scale;
    float m = metric[(size_t)n * HW + p];
    float e = eweight(m);
    float dxe = dx * e, dye = dy * e;
    float gx = (float)x + dx;
    float gy = (float)y + dy;
    float x0f = floorf(gx), y0f = floorf(gy);
    float fx = gx - x0f, fy = gy - y0f;
    int x0 = (int)x0f, y0 = (int)y0f;

#pragma unroll 4
    for (int i = 0; i < 64; ++i) {
        float fxi = __shfl(fx, i);
        float fyi = __shfl(fy, i);
        float ei = __shfl(e, i);
        float dxei = __shfl(dxe, i);
        float dyei = __shfl(dye, i);
        int x0b = __shfl(x0, i);
        int y0b = __shfl(y0, i);

        if (lane < 16) {
            int row = lane >> 3, slot = lane & 7, crn = slot >> 2, ch = slot & 3;
            int yt = y0b + row;
            int xt = x0b + crn;
            if ((unsigned)xt < (unsigned)W && (unsigned)yt < (unsigned)H) {
                float wr = (crn ? fxi : 1.0f - fxi) * (row ? fyi : 1.0f - fyi);
                float v = (ch == 0) ? dxei : (ch == 1) ? dyei : (ch == 2) ? ei : 0.0f;
                atomicAdd(&num[(((long long)n * H + yt) * (long long)W + x0b) * 4 + slot], wr * v);
            }
        }
    }
}

__global__ __launch_bounds__(256) void norm_flow(const float* __restrict__ num,
                                                 float* __restrict__ out, int HW, int total) {
    int q = blockIdx.x * blockDim.x + threadIdx.x;
    if (q >= total) return;
    float4 v = ((const float4*)num)[q];
    int n = q / HW;
    int p = q - n * HW;
    float inv = -1.0f / (v.z + EPS);
    out[((size_t)n * 2 + 0) * HW + p] = v.x * inv;
    out[((size_t)n * 2 + 1) * HW + p] = v.y * inv;
}

// ---------------------------------------------------------------------------
extern "C" void kernel_launch(void* const* d_in, const int* in_sizes, int n_in,
                              void* d_out, int out_size, void* d_ws, size_t ws_size,
                              hipStream_t stream) {
    const float* x1_0 = (const float*)d_in[0];
    const float* x1_1 = (const float*)d_in[2];
    const float* x1_2 = (const float*)d_in[4];
    const float* m1t  = (const float*)d_in[6];
    const float* m2t  = (const float*)d_in[7];
    const float* F12  = (const float*)d_in[8];
    const float* F21  = (const float*)d_in[9];

    const int N = 4;
    const int H0 = 256, W0 = 448;
    const int H1 = 128, W1 = 224;
    const int H2 = 64,  W2 = 112;
    const int HW0 = H0 * W0, HW1 = H1 * W1, HW2 = H2 * W2;
    const int NHW0 = N * HW0, NHW1 = N * HW1, NHW2 = N * HW2;

    // d_out layout (floats), reference return order
    const size_t o0 = 0;
    const size_t o1 = o0 + (size_t)N * 32 * HW0;
    const size_t o2 = o1 + (size_t)N * 64 * HW1;
    const size_t o3 = o2 + (size_t)N * 96 * HW2;
    const size_t o4 = o3 + (size_t)NHW0;
    const size_t o5 = o4 + (size_t)NHW1;
    const size_t o6 = o5 + (size_t)NHW2;
    float* out = (float*)d_out;

    // ws layout: [numF (zeroed) | rec counters (zeroed) | rec lists | small | num/dh buffers]
    float* ws_f = (float*)d_ws;
    float* numF = ws_f;                                   // NHW0*4, zeroed
    int* cnts = (int*)(numF + (size_t)NHW0 * 4);          // 4 ints (3 used), zeroed
    unsigned* list0 = (unsigned*)(cnts + 4);              // 32768
    unsigned* list1 = list0 + 32768;                      // 2048
    unsigned* list2 = list1 + 2048;                       // 2048
    float* flow1   = (float*)(list2 + 2048);              // 2*NHW1
    float* metric1 = flow1 + (size_t)2 * NHW1;            // NHW1
    float* flow2   = metric1 + NHW1;                      // 2*NHW2
    float* metric2 = flow2 + (size_t)2 * NHW2;            // NHW2
    float* num0 = metric2 + NHW2;                         // N*32*HW0
    float* dh0  = num0 + (size_t)N * 32 * HW0;            // NHW0*2
    float* num1 = dh0 + (size_t)NHW0 * 2;                 // N*64*HW1
    float* dh1  = num1 + (size_t)N * 64 * HW1;            // NHW1*2
    float* num2 = dh1 + (size_t)NHW1 * 2;                 // N*96*HW2
    float* dh2  = num2 + (size_t)N * 96 * HW2;            // NHW2*2

    hipMemsetAsync(ws_f, 0, ((size_t)NHW0 * 4 + 4) * sizeof(float), stream);

    const int B = 256;

    // pyramid resizes (flow scale folded: F1t = 0.5*F12)
    downsample2_kernel<<<cdiv_i(N * 1 * HW1, B), B, 0, stream>>>(m1t, metric1, N, H0, W0, 1.0f);
    downsample2_kernel<<<cdiv_i(N * 2 * HW1, B), B, 0, stream>>>(F12, flow1, N * 2, H0, W0, 0.25f);
    downsample2_kernel<<<cdiv_i(N * 1 * HW2, B), B, 0, stream>>>(metric1, metric2, N, H1, W1, 1.0f);
    downsample2_kernel<<<cdiv_i(N * 2 * HW2, B), B, 0, stream>>>(flow1, flow2, N * 2, H1, W1, 0.5f);

    // channel-split privatized splats
    // L0: 448 tiles x (4 ch-groups + den) = 2240 blocks of 448 thr (K=7)
    splat_tile2<32, 256, 448, 32, 12, 8, 448><<<2240, 448, 0, stream>>>(
        x1_0, F12, 0.5f, m1t, num0, dh0, cnts + 0, list0, 32768);
    // L1: 448 tiles x (4+1) = 2240 blocks of 192 thr (K=3)
    splat_tile2<64, 128, 224, 16, 4, 16, 192><<<2240, 192, 0, stream>>>(
        x1_1, flow1, 1.0f, metric1, num1, dh1, cnts + 1, list1, 2048);
    // L2: 448 tiles x (3+1) = 1792 blocks of 256 thr (K=1)
    splat_tile2<96, 64, 112, 8, 4, 32, 256><<<1792, 256, 0, stream>>>(
        x1_2, flow2, 1.0f, metric2, num2, dh2, cnts + 2, list2, 2048);
    splat_flow<256, 448><<<NHW0 / 256, 256, 0, stream>>>(F21, 0.5f, m2t, numF);

    // rare far-flow fixups (before normalization)
    splat_fixup<32, 256, 448, 32, 12><<<2048, 128, 0, stream>>>(
        x1_0, F12, 0.5f, m1t, num0, dh0, cnts + 0, list0, 32768);
    splat_fixup<64, 128, 224, 16, 4><<<256, 128, 0, stream>>>(
        x1_1, flow1, 1.0f, metric1, num1, dh1, cnts + 1, list1, 2048);
    splat_fixup<96, 64, 112, 8, 4><<<256, 128, 0, stream>>>(
        x1_2, flow2, 1.0f, metric2, num2, dh2, cnts + 2, list2, 2048);

    // normalize (NCHW, no transpose needed) + hole masks
    norm_nchw<32, 256, 448><<<cdiv_i(N * 32 * HW0 / 4, B), B, 0, stream>>>(num0, dh0, out + o0, out + o3);
    norm_nchw<64, 128, 224><<<cdiv_i(N * 64 * HW1 / 4, B), B, 0, stream>>>(num1, dh1, out + o1, out + o4);
    norm_nchw<96, 64, 112><<<cdiv_i(N * 96 * HW2 / 4, B), B, 0, stream>>>(num2, dh2, out + o2, out + o5);
    norm_flow<<<cdiv_i(NHW0, B), B, 0, stream>>>(numF, out + o6, HW0, NHW0);
}

// Round 4
// 730.049 us; speedup vs baseline: 1.3486x; 1.2946x over previous
//
#include <hip/hip_runtime.h>

#define EPS 1e-7f

static inline int cdiv_i(int a, int b) { return (a + b - 1) / b; }

__device__ __forceinline__ float eweight(float m) {
    return expf(fminf(fmaxf(-m, -20.0f), 20.0f));
}

// ---------------------------------------------------------------------------
// Exact factor-2 bilinear+antialias downsample (jax.image.resize semantics)
// ---------------------------------------------------------------------------
__global__ void downsample2_kernel(const float* __restrict__ in, float* __restrict__ out,
                                   int NC, int Hin, int Win, float scale) {
    const int Hout = Hin >> 1, Wout = Win >> 1;
    const int HWo = Hout * Wout;
    int idx = blockIdx.x * blockDim.x + threadIdx.x;
    if (idx >= NC * HWo) return;
    int nc = idx / HWo;
    int p = idx - nc * HWo;
    int i = p / Wout;
    int j = p - i * Wout;

    const float kk[4] = { 0.25f, 0.75f, 0.75f, 0.25f };
    float wy[4], wx[4], sy = 0.0f, sx = 0.0f;
    int r0 = 2 * i - 1, c0 = 2 * j - 1;
#pragma unroll
    for (int a = 0; a < 4; ++a) {
        int ra = r0 + a;
        wy[a] = (ra >= 0 && ra < Hin) ? kk[a] : 0.0f;
        sy += wy[a];
        int cb = c0 + a;
        wx[a] = (cb >= 0 && cb < Win) ? kk[a] : 0.0f;
        sx += wx[a];
    }
#pragma unroll
    for (int a = 0; a < 4; ++a) { wy[a] /= sy; wx[a] /= sx; }

    const float* base = in + (size_t)nc * Hin * Win;
    float acc = 0.0f;
#pragma unroll
    for (int a = 0; a < 4; ++a) {
        int ra = r0 + a;
        if (ra < 0 || ra >= Hin) continue;
        const float* row = base + (size_t)ra * Win;
        float racc = 0.0f;
#pragma unroll
        for (int b = 0; b < 4; ++b) {
            int cb = c0 + b;
            if (cb < 0 || cb >= Win) continue;
            racc += wx[b] * row[cb];
        }
        acc += wy[a] * racc;
    }
    out[(size_t)nc * HWo + p] = acc * scale;
}

// ---------------------------------------------------------------------------
// Bucketed-GATHER soft-splat (no atomics on the hot path).
// Block owns a T x T target tile. Phase 1: stage region sources' (e,fx,fy)
// records in LDS and bucket each source index by its target cell
// (cell = floor(s+flow) - tile_origin + 1; one LDS atomicInc per source).
// Phase 2 (per CB-channel pass): stage features coalesced into LDS, then
// each thread PULLS its target pixel's contributions from 4 cells via plain
// ds_reads, accumulating in registers; plain coalesced stores to num (NCHW).
// den/wsum computed in pass 0. Far-flow sources -> record list -> fixup.
// ---------------------------------------------------------------------------
template <int C, int H, int W, int T, int R, int CB, int THREADS>
__global__ __launch_bounds__(THREADS) void splat_gather(
        const float* __restrict__ feat, const float* __restrict__ flow, float flow_scale,
        const float* __restrict__ metric, float* __restrict__ num, float* __restrict__ dh,
        int* __restrict__ rec_cnt, unsigned* __restrict__ rec_list, int rec_cap) {
    constexpr int HW = H * W;
    constexpr int RW = T + 2 * R;
    constexpr int RS = RW * RW;
    constexpr int RSP = RS + 1;          // odd stride for bank spread
    constexpr int GRIDC = (T + 2) * (T + 2);
    constexpr int CAP = 8;
    constexpr int XCAP = 256;
    constexpr int TT = T * T;
    constexpr int SUB = THREADS / TT;    // threads per target pixel
    constexpr int CPT = CB / SUB;        // channels per thread per pass
    constexpr int TILES_X = W / T;
    constexpr int TILES = (W / T) * (H / T);
    constexpr int KCH = (RS + THREADS - 1) / THREADS;
    constexpr int PASSES = C / CB;

    __shared__ float4 srec[RS];
    __shared__ float sfeat[CB * RSP];
    __shared__ int scnt[GRIDC];
    __shared__ unsigned short slist[GRIDC * CAP];
    __shared__ unsigned sextra[XCAP];
    __shared__ int sxcnt;

    const int tid = threadIdx.x;
    int b = blockIdx.x;
    const int n = b / TILES;
    const int tt = b - n * TILES;
    const int ty0 = (tt / TILES_X) * T;
    const int tx0 = (tt - (tt / TILES_X) * TILES_X) * T;

    for (int i = tid; i < GRIDC; i += THREADS) scnt[i] = 0;
    if (tid == 0) sxcnt = 0;
    __syncthreads();

    const float* flowx = flow + (size_t)(n * 2 + 0) * HW;
    const float* flowy = flow + (size_t)(n * 2 + 1) * HW;
    const float* met = metric + (size_t)n * HW;

    // ---- phase 1: geometry, records, buckets
    for (int k = 0; k < KCH; ++k) {
        int r = tid + k * THREADS;
        if (r >= RS) break;
        int ry = r / RW, rx = r - ry * RW;
        int sy = ty0 - R + ry, sx = tx0 - R + rx;
        if ((unsigned)sx >= (unsigned)W || (unsigned)sy >= (unsigned)H) continue;
        int sp = sy * W + sx;
        float dx = flowx[sp] * flow_scale;
        float dy = flowy[sp] * flow_scale;
        float e = eweight(met[sp]);
        float gx = (float)sx + dx, gy = (float)sy + dy;
        float x0f = floorf(gx), y0f = floorf(gy);
        float fx = gx - x0f, fy = gy - y0f;
        int x0 = (int)x0f, y0 = (int)y0f;
        srec[r] = make_float4(e, fx, fy, 0.f);
        int cy = y0 - ty0 + 1, cx = x0 - tx0 + 1;
        if ((unsigned)cy < (unsigned)(T + 2) && (unsigned)cx < (unsigned)(T + 2)) {
            int cell = cy * (T + 2) + cx;
            int idx = atomicAdd(&scnt[cell], 1);
            if (idx < CAP) slist[cell * CAP + idx] = (unsigned short)r;
            else {
                int xi = atomicAdd(&sxcnt, 1);
                if (xi < XCAP) sextra[xi] = (unsigned)r | ((unsigned)cell << 12);
            }
        }
        // far-flow record emission (owner tile of s only)
        bool owned = rx >= R && rx < R + T && ry >= R && ry < R + T;
        if (owned) {
            int dxo = x0 - sx, dyo = y0 - sy;
            if (dxo < -(R - 1) || dxo > R - 2 || dyo < -(R - 1) || dyo > R - 2) {
                bool miss = false;
#pragma unroll
                for (int ci = 0; ci < 2; ++ci)
#pragma unroll
                    for (int cj = 0; cj < 2; ++cj) {
                        int cxx = x0 + cj, cyy = y0 + ci;
                        if ((unsigned)cxx < (unsigned)W && (unsigned)cyy < (unsigned)H) {
                            int bx0 = (cxx / T) * T, by0 = (cyy / T) * T;
                            if (sx < bx0 - R || sx >= bx0 + T + R ||
                                sy < by0 - R || sy >= by0 + T + R) miss = true;
                        }
                    }
                if (miss) {
                    int ridx = atomicAdd(rec_cnt, 1);
                    if (ridx < rec_cap) rec_list[ridx] = (unsigned)(n * HW + sp);
                }
            }
        }
    }
    __syncthreads();

    // ---- per-target cell handles (constant across passes)
    const int tgt = tid % TT;
    const int q = tid / TT;
    const int trow = tgt / T, tcol = tgt - trow * T;
    const int c0 = (trow + 1) * (T + 2) + (tcol + 1);  // corner00: w=(1-fx)(1-fy)
    const int c1 = (trow + 1) * (T + 2) + tcol;        // corner10: w=fx(1-fy)
    const int c2 = trow * (T + 2) + (tcol + 1);        // corner01: w=(1-fx)fy
    const int c3 = trow * (T + 2) + tcol;              // corner11: w=fx*fy
    const int n0 = scnt[c0] < CAP ? scnt[c0] : CAP;
    const int n1 = scnt[c1] < CAP ? scnt[c1] : CAP;
    const int n2 = scnt[c2] < CAP ? scnt[c2] : CAP;
    const int n3 = scnt[c3] < CAP ? scnt[c3] : CAP;
    const int xt = sxcnt < XCAP ? sxcnt : XCAP;
    const int cum0 = n0, cum1 = n0 + n1, cum2 = n0 + n1 + n2, tot = cum2 + n3;

    // ---- phase 2: channel passes
    for (int pass = 0; pass < PASSES; ++pass) {
        for (int i = tid; i < CB * RS; i += THREADS) {
            int u = i / RS, r = i - u * RS;
            int ry = r / RW, rx = r - ry * RW;
            int sy = ty0 - R + ry, sx = tx0 - R + rx;
            float v = 0.f;
            if ((unsigned)sx < (unsigned)W && (unsigned)sy < (unsigned)H)
                v = feat[((size_t)n * C + pass * CB + u) * HW + sy * W + sx];
            sfeat[u * RSP + r] = v;
        }
        __syncthreads();

        float acc[CPT];
#pragma unroll
        for (int u = 0; u < CPT; ++u) acc[u] = 0.f;
        float den = 0.f, wsm = 0.f;

        for (int i = 0; i < tot; ++i) {
            int j, kk, cell;
            if (i < cum0)      { j = 0; kk = i;        cell = c0; }
            else if (i < cum1) { j = 1; kk = i - cum0; cell = c1; }
            else if (i < cum2) { j = 2; kk = i - cum1; cell = c2; }
            else               { j = 3; kk = i - cum2; cell = c3; }
            int r = slist[cell * CAP + kk];
            float4 rc = srec[r];
            float wx = (j & 1) ? rc.y : 1.f - rc.y;
            float wy = (j & 2) ? rc.z : 1.f - rc.z;
            float bil = wx * wy;
            float w = rc.x * bil;
#pragma unroll
            for (int u = 0; u < CPT; ++u)
                acc[u] += w * sfeat[(q * CPT + u) * RSP + r];
            den += w; wsm += bil;
        }
        // extras (bucket overflow; astronomically rare with Poisson(1) cells)
        for (int i = 0; i < xt; ++i) {
            unsigned pk = sextra[i];
            int r = pk & 0xFFF;
            int cell = pk >> 12;
            int j = (cell == c0) ? 0 : (cell == c1) ? 1 : (cell == c2) ? 2 : (cell == c3) ? 3 : -1;
            if (j >= 0) {
                float4 rc = srec[r];
                float wx = (j & 1) ? rc.y : 1.f - rc.y;
                float wy = (j & 2) ? rc.z : 1.f - rc.z;
                float bil = wx * wy;
                float w = rc.x * bil;
#pragma unroll
                for (int u = 0; u < CPT; ++u)
                    acc[u] += w * sfeat[(q * CPT + u) * RSP + r];
                den += w; wsm += bil;
            }
        }

        size_t tp = (size_t)(ty0 + trow) * W + tx0 + tcol;
#pragma unroll
        for (int u = 0; u < CPT; ++u)
            num[((size_t)n * C + pass * CB + q * CPT + u) * HW + tp] = acc[u];
        if (pass == 0 && q == 0)
            *(float2*)(dh + ((size_t)n * HW + tp) * 2) = make_float2(den, wsm);
        __syncthreads();
    }
}

// ---------------------------------------------------------------------------
// Apply the rare far-flow contributions with global atomics, parallel over
// (corner, channel). Runs after splat_gather, before normalization.
// ---------------------------------------------------------------------------
template <int C, int H, int W, int T, int R>
__global__ __launch_bounds__(128) void splat_fixup(
        const float* __restrict__ feat, const float* __restrict__ flow, float flow_scale,
        const float* __restrict__ metric, float* __restrict__ num, float* __restrict__ dh,
        const int* __restrict__ rec_cnt, const unsigned* __restrict__ rec_list, int rec_cap) {
    constexpr int HW = H * W;
    int cnt = *rec_cnt;
    if (cnt > rec_cap) cnt = rec_cap;
    for (int rec = blockIdx.x; rec < cnt; rec += gridDim.x) {
        unsigned qv = rec_list[rec];
        int n = qv / HW;
        int p = qv - n * HW;
        int sy = p / W;
        int sx = p - sy * W;
        float dx = flow[(size_t)(n * 2 + 0) * HW + p] * flow_scale;
        float dy = flow[(size_t)(n * 2 + 1) * HW + p] * flow_scale;
        float e = eweight(metric[(size_t)n * HW + p]);
        float gx = (float)sx + dx, gy = (float)sy + dy;
        float x0f = floorf(gx), y0f = floorf(gy);
        float fx = gx - x0f, fy = gy - y0f;
        int x0 = (int)x0f, y0 = (int)y0f;
        float wxs[2] = { 1.f - fx, fx }, wys[2] = { 1.f - fy, fy };
        for (int idx = threadIdx.x; idx < 4 * C; idx += 128) {
            int corner = idx / C;
            int c = idx - corner * C;
            int ci = corner >> 1, cj = corner & 1;
            int cx = x0 + cj, cy = y0 + ci;
            if ((unsigned)cx >= (unsigned)W || (unsigned)cy >= (unsigned)H) continue;
            int bx0 = (cx / T) * T, by0 = (cy / T) * T;
            bool miss = sx < bx0 - R || sx >= bx0 + T + R ||
                        sy < by0 - R || sy >= by0 + T + R;
            if (!miss) continue;  // applied by owner block already
            float w = wxs[cj] * wys[ci];
            atomicAdd(&num[((size_t)n * C + c) * HW + (size_t)cy * W + cx],
                      feat[((size_t)n * C + c) * HW + p] * (e * w));
            if (c == 0) {
                size_t tp = ((size_t)n * H + cy) * W + cx;
                atomicAdd(&dh[tp * 2], e * w);
                atomicAdd(&dh[tp * 2 + 1], w);
            }
        }
    }
}

// ---------------------------------------------------------------------------
// NCHW normalize + hole mask (c==0 lanes). float4-vectorized.
// ---------------------------------------------------------------------------
template <int C, int H, int W>
__global__ __launch_bounds__(256) void norm_nchw(const float* __restrict__ num,
                                                 const float* __restrict__ dh,
                                                 float* __restrict__ out,
                                                 float* __restrict__ hole) {
    constexpr int HW = H * W;
    constexpr int N = 4;
    int q4 = blockIdx.x * 256 + threadIdx.x;
    if (q4 >= N * C * HW / 4) return;
    int idx = q4 * 4;
    int per = C * HW;
    int n = idx / per;
    int rem = idx - n * per;
    int c = rem / HW;
    int p = rem - c * HW;
    float4 v = *(const float4*)(num + idx);
    const float2* dp = (const float2*)(dh + ((size_t)n * HW + p) * 2);
    float2 d0 = dp[0], d1 = dp[1], d2 = dp[2], d3 = dp[3];
    float4 o;
    o.x = v.x / (d0.x + EPS);
    o.y = v.y / (d1.x + EPS);
    o.z = v.z / (d2.x + EPS);
    o.w = v.w / (d3.x + EPS);
    *(float4*)(out + idx) = o;
    if (c == 0) {
        float4 hm;
        hm.x = (d0.y / (d0.y + EPS) <= 0.5f) ? 1.f : 0.f;
        hm.y = (d1.y / (d1.y + EPS) <= 0.5f) ? 1.f : 0.f;
        hm.z = (d2.y / (d2.y + EPS) <= 0.5f) ? 1.f : 0.f;
        hm.w = (d3.y / (d3.y + EPS) <= 0.5f) ? 1.f : 0.f;
        *(float4*)(hole + (size_t)n * HW + p) = hm;
    }
}

// ---------------------------------------------------------------------------
// Ft2 splat: channels {dx*e, dy*e, e, pad} packed CS=4, pair-merged. (kept)
// ---------------------------------------------------------------------------
template <int H, int W>
__global__ __launch_bounds__(256) void splat_flow(const float* __restrict__ flow, float flow_scale,
                                                  const float* __restrict__ metric,
                                                  float* __restrict__ num) {
    constexpr int HW = H * W;
    const int lane = threadIdx.x & 63;
    const int wid = blockIdx.x * 4 + (threadIdx.x >> 6);
    const int q0 = wid * 64;
    const int n = q0 / HW;
    const int p0 = q0 - n * HW;

    const int p = p0 + lane;
    int y = p / W;
    int x = p - y * W;
    float dx = flow[(size_t)(n * 2 + 0) * HW + p] * flow_scale;
    float dy = flow[(size_t)(n * 2 + 1) * HW + p] * flow_scale;
    float m = metric[(size_t)n * HW + p];
    float e = eweight(m);
    float dxe = dx * e, dye = dy * e;
    float gx = (float)x + dx;
    float gy = (float)y + dy;
    float x0f = floorf(gx), y0f = floorf(gy);
    float fx = gx - x0f, fy = gy - y0f;
    int x0 = (int)x0f, y0 = (int)y0f;

#pragma unroll 4
    for (int i = 0; i < 64; ++i) {
        float fxi = __shfl(fx, i);
        float fyi = __shfl(fy, i);
        float ei = __shfl(e, i);
        float dxei = __shfl(dxe, i);
        float dyei = __shfl(dye, i);
        int x0b = __shfl(x0, i);
        int y0b = __shfl(y0, i);

        if (lane < 16) {
            int row = lane >> 3, slot = lane & 7, crn = slot >> 2, ch = slot & 3;
            int yt = y0b + row;
            int xt = x0b + crn;
            if ((unsigned)xt < (unsigned)W && (unsigned)yt < (unsigned)H) {
                float wr = (crn ? fxi : 1.0f - fxi) * (row ? fyi : 1.0f - fyi);
                float v = (ch == 0) ? dxei : (ch == 1) ? dyei : (ch == 2) ? ei : 0.0f;
                atomicAdd(&num[(((long long)n * H + yt) * (long long)W + x0b) * 4 + slot], wr * v);
            }
        }
    }
}

__global__ __launch_bounds__(256) void norm_flow(const float* __restrict__ num,
                                                 float* __restrict__ out, int HW, int total) {
    int q = blockIdx.x * blockDim.x + threadIdx.x;
    if (q >= total) return;
    float4 v = ((const float4*)num)[q];
    int n = q / HW;
    int p = q - n * HW;
    float inv = -1.0f / (v.z + EPS);
    out[((size_t)n * 2 + 0) * HW + p] = v.x * inv;
    out[((size_t)n * 2 + 1) * HW + p] = v.y * inv;
}

// ---------------------------------------------------------------------------
extern "C" void kernel_launch(void* const* d_in, const int* in_sizes, int n_in,
                              void* d_out, int out_size, void* d_ws, size_t ws_size,
                              hipStream_t stream) {
    const float* x1_0 = (const float*)d_in[0];
    const float* x1_1 = (const float*)d_in[2];
    const float* x1_2 = (const float*)d_in[4];
    const float* m1t  = (const float*)d_in[6];
    const float* m2t  = (const float*)d_in[7];
    const float* F12  = (const float*)d_in[8];
    const float* F21  = (const float*)d_in[9];

    const int N = 4;
    const int H0 = 256, W0 = 448;
    const int H1 = 128, W1 = 224;
    const int H2 = 64,  W2 = 112;
    const int HW0 = H0 * W0, HW1 = H1 * W1, HW2 = H2 * W2;
    const int NHW0 = N * HW0, NHW1 = N * HW1, NHW2 = N * HW2;

    // d_out layout (floats), reference return order
    const size_t o0 = 0;
    const size_t o1 = o0 + (size_t)N * 32 * HW0;
    const size_t o2 = o1 + (size_t)N * 64 * HW1;
    const size_t o3 = o2 + (size_t)N * 96 * HW2;
    const size_t o4 = o3 + (size_t)NHW0;
    const size_t o5 = o4 + (size_t)NHW1;
    const size_t o6 = o5 + (size_t)NHW2;
    float* out = (float*)d_out;

    // ws layout: [numF (zeroed) | rec counters (zeroed) | rec lists | small | num/dh buffers]
    float* ws_f = (float*)d_ws;
    float* numF = ws_f;                                   // NHW0*4, zeroed
    int* cnts = (int*)(numF + (size_t)NHW0 * 4);          // 4 ints (3 used), zeroed
    unsigned* list0 = (unsigned*)(cnts + 4);              // 32768
    unsigned* list1 = list0 + 32768;                      // 2048
    unsigned* list2 = list1 + 2048;                       // 2048
    float* flow1   = (float*)(list2 + 2048);              // 2*NHW1
    float* metric1 = flow1 + (size_t)2 * NHW1;            // NHW1
    float* flow2   = metric1 + NHW1;                      // 2*NHW2
    float* metric2 = flow2 + (size_t)2 * NHW2;            // NHW2
    float* num0 = metric2 + NHW2;                         // N*32*HW0
    float* dh0  = num0 + (size_t)N * 32 * HW0;            // NHW0*2
    float* num1 = dh0 + (size_t)NHW0 * 2;                 // N*64*HW1
    float* dh1  = num1 + (size_t)N * 64 * HW1;            // NHW1*2
    float* num2 = dh1 + (size_t)NHW1 * 2;                 // N*96*HW2
    float* dh2  = num2 + (size_t)N * 96 * HW2;            // NHW2*2

    hipMemsetAsync(ws_f, 0, ((size_t)NHW0 * 4 + 4) * sizeof(float), stream);

    const int B = 256;

    // pyramid resizes (flow scale folded: F1t = 0.5*F12)
    downsample2_kernel<<<cdiv_i(N * 1 * HW1, B), B, 0, stream>>>(m1t, metric1, N, H0, W0, 1.0f);
    downsample2_kernel<<<cdiv_i(N * 2 * HW1, B), B, 0, stream>>>(F12, flow1, N * 2, H0, W0, 0.25f);
    downsample2_kernel<<<cdiv_i(N * 1 * HW2, B), B, 0, stream>>>(metric1, metric2, N, H1, W1, 1.0f);
    downsample2_kernel<<<cdiv_i(N * 2 * HW2, B), B, 0, stream>>>(flow1, flow2, N * 2, H1, W1, 0.5f);

    // bucketed-gather splats (no atomics on the hot path)
    // L0: T=16,R=12,CB=4 -> 4*(28*16)=1792 blocks of 512 (LDS ~59KB, 2 blk/CU)
    splat_gather<32, 256, 448, 16, 12, 4, 512><<<1792, 512, 0, stream>>>(
        x1_0, F12, 0.5f, m1t, num0, dh0, cnts + 0, list0, 32768);
    // L1: T=16,R=4,CB=16 -> 4*(14*8)=448 blocks of 512 (LDS ~54KB)
    splat_gather<64, 128, 224, 16, 4, 16, 512><<<448, 512, 0, stream>>>(
        x1_1, flow1, 1.0f, metric1, num1, dh1, cnts + 1, list1, 2048);
    // L2: T=8,R=4,CB=32 -> 448 blocks of 256 (LDS ~40KB)
    splat_gather<96, 64, 112, 8, 4, 32, 256><<<448, 256, 0, stream>>>(
        x1_2, flow2, 1.0f, metric2, num2, dh2, cnts + 2, list2, 2048);
    splat_flow<256, 448><<<NHW0 / 256, 256, 0, stream>>>(F21, 0.5f, m2t, numF);

    // rare far-flow fixups (before normalization)
    splat_fixup<32, 256, 448, 16, 12><<<2048, 128, 0, stream>>>(
        x1_0, F12, 0.5f, m1t, num0, dh0, cnts + 0, list0, 32768);
    splat_fixup<64, 128, 224, 16, 4><<<256, 128, 0, stream>>>(
        x1_1, flow1, 1.0f, metric1, num1, dh1, cnts + 1, list1, 2048);
    splat_fixup<96, 64, 112, 8, 4><<<256, 128, 0, stream>>>(
        x1_2, flow2, 1.0f, metric2, num2, dh2, cnts + 2, list2, 2048);

    // normalize (NCHW, no transpose needed) + hole masks
    norm_nchw<32, 256, 448><<<cdiv_i(N * 32 * HW0 / 4, B), B, 0, stream>>>(num0, dh0, out + o0, out + o3);
    norm_nchw<64, 128, 224><<<cdiv_i(N * 64 * HW1 / 4, B), B, 0, stream>>>(num1, dh1, out + o1, out + o4);
    norm_nchw<96, 64, 112><<<cdiv_i(N * 96 * HW2 / 4, B), B, 0, stream>>>(num2, dh2, out + o2, out + o5);
    norm_flow<<<cdiv_i(NHW0, B), B, 0, stream>>>(numF, out + o6, HW0, NHW0);
}

// Round 5
// 505.810 us; speedup vs baseline: 1.9465x; 1.4433x over previous
//
#include <hip/hip_runtime.h>

#define EPS 1e-7f

static inline int cdiv_i(int a, int b) { return (a + b - 1) / b; }

__device__ __forceinline__ float eweight(float m) {
    return expf(fminf(fmaxf(-m, -20.0f), 20.0f));
}

// ---------------------------------------------------------------------------
// Exact factor-2 bilinear+antialias downsample (jax.image.resize semantics)
// ---------------------------------------------------------------------------
__global__ void downsample2_kernel(const float* __restrict__ in, float* __restrict__ out,
                                   int NC, int Hin, int Win, float scale) {
    const int Hout = Hin >> 1, Wout = Win >> 1;
    const int HWo = Hout * Wout;
    int idx = blockIdx.x * blockDim.x + threadIdx.x;
    if (idx >= NC * HWo) return;
    int nc = idx / HWo;
    int p = idx - nc * HWo;
    int i = p / Wout;
    int j = p - i * Wout;

    const float kk[4] = { 0.25f, 0.75f, 0.75f, 0.25f };
    float wy[4], wx[4], sy = 0.0f, sx = 0.0f;
    int r0 = 2 * i - 1, c0 = 2 * j - 1;
#pragma unroll
    for (int a = 0; a < 4; ++a) {
        int ra = r0 + a;
        wy[a] = (ra >= 0 && ra < Hin) ? kk[a] : 0.0f;
        sy += wy[a];
        int cb = c0 + a;
        wx[a] = (cb >= 0 && cb < Win) ? kk[a] : 0.0f;
        sx += wx[a];
    }
#pragma unroll
    for (int a = 0; a < 4; ++a) { wy[a] /= sy; wx[a] /= sx; }

    const float* base = in + (size_t)nc * Hin * Win;
    float acc = 0.0f;
#pragma unroll
    for (int a = 0; a < 4; ++a) {
        int ra = r0 + a;
        if (ra < 0 || ra >= Hin) continue;
        const float* row = base + (size_t)ra * Win;
        float racc = 0.0f;
#pragma unroll
        for (int b = 0; b < 4; ++b) {
            int cb = c0 + b;
            if (cb < 0 || cb >= Win) continue;
            racc += wx[b] * row[cb];
        }
        acc += wy[a] * racc;
    }
    out[(size_t)nc * HWo + p] = acc * scale;
}

// ---------------------------------------------------------------------------
// Bucketed-GATHER soft-splat, channel-split across blocks (one staging pass
// per block). Grid = N*TILES*GROUPS, g = blockIdx % GROUPS handles channels
// [g*CB, g*CB+CB). Load order: flow/metric first, features second -> phase-1
// geometry only drains the flow loads; feature loads stay in flight until
// the single barrier. Group 0 also computes den/wsum and emits far-flow
// records (exactly once per source).
// ---------------------------------------------------------------------------
template <int C, int H, int W, int T, int R, int CB, int THREADS>
__global__ __launch_bounds__(THREADS) void splat_gather2(
        const float* __restrict__ feat, const float* __restrict__ flow, float flow_scale,
        const float* __restrict__ metric, float* __restrict__ num, float* __restrict__ dh,
        int* __restrict__ rec_cnt, unsigned* __restrict__ rec_list, int rec_cap) {
    constexpr int HW = H * W;
    constexpr int RW = T + 2 * R;
    constexpr int RS = RW * RW;
    constexpr int GRIDC = (T + 2) * (T + 2);
    constexpr int CAP = 8;
    constexpr int XCAP = 256;
    constexpr int TT = T * T;
    constexpr int SUB = THREADS / TT;
    constexpr int CPT = CB / SUB;
    constexpr int TILES_X = W / T;
    constexpr int TILES = TILES_X * (H / T);
    constexpr int GROUPS = C / CB;
    constexpr int KCH = (RS + THREADS - 1) / THREADS;
    constexpr int KS = (CB * RS + THREADS - 1) / THREADS;

    __shared__ float4 srec[RS];
    __shared__ float sfeat[CB * RS];
    __shared__ int scnt[GRIDC];
    __shared__ unsigned short slist[GRIDC * CAP];
    __shared__ unsigned sextra[XCAP];
    __shared__ int sxcnt;

    const int tid = threadIdx.x;
    int b = blockIdx.x;
    const int g = b % GROUPS;
    b /= GROUPS;
    const int n = b / TILES;
    const int tt = b - n * TILES;
    const int ty0 = (tt / TILES_X) * T;
    const int tx0 = (tt - (tt / TILES_X) * TILES_X) * T;

    for (int i = tid; i < GRIDC; i += THREADS) scnt[i] = 0;
    if (tid == 0) sxcnt = 0;
    __syncthreads();

    const float* flowx = flow + (size_t)(n * 2 + 0) * HW;
    const float* flowy = flow + (size_t)(n * 2 + 1) * HW;
    const float* met = metric + (size_t)n * HW;
    const float* fbase = feat + ((size_t)n * C + (size_t)g * CB) * HW;

    // ---- phase 0: issue loads (flow/metric FIRST, features SECOND)
    float fdx[KCH], fdy[KCH], fme[KCH];
    bool val[KCH];
#pragma unroll
    for (int k = 0; k < KCH; ++k) {
        int r = tid + k * THREADS;
        int ry = r / RW, rx = r - ry * RW;
        int sy = ty0 - R + ry, sx = tx0 - R + rx;
        bool v = (r < RS) && ((unsigned)sx < (unsigned)W) && ((unsigned)sy < (unsigned)H);
        int sp = v ? sy * W + sx : 0;
        val[k] = v;
        fdx[k] = flowx[sp];
        fdy[k] = flowy[sp];
        fme[k] = met[sp];
    }
    float fst[KS];
#pragma unroll
    for (int k = 0; k < KS; ++k) {
        int idx = tid + k * THREADS;
        if (idx < CB * RS) {
            int u = idx / RS, r = idx - u * RS;
            int ry = r / RW, rx = r - ry * RW;
            int sy = ty0 - R + ry, sx = tx0 - R + rx;
            int sp = ((unsigned)sx < (unsigned)W && (unsigned)sy < (unsigned)H) ? sy * W + sx : 0;
            fst[k] = fbase[(size_t)u * HW + sp];
        }
    }

    // ---- phase 1: geometry + buckets (+ records, group 0 only)
#pragma unroll
    for (int k = 0; k < KCH; ++k) {
        if (!val[k]) continue;
        int r = tid + k * THREADS;
        int ry = r / RW, rx = r - ry * RW;
        int sy = ty0 - R + ry, sx = tx0 - R + rx;
        float dx = fdx[k] * flow_scale;
        float dy = fdy[k] * flow_scale;
        float e = eweight(fme[k]);
        float gx = (float)sx + dx, gy = (float)sy + dy;
        float x0f = floorf(gx), y0f = floorf(gy);
        int x0 = (int)x0f, y0 = (int)y0f;
        srec[r] = make_float4(e, gx - x0f, gy - y0f, 0.f);
        int cy = y0 - ty0 + 1, cx = x0 - tx0 + 1;
        if ((unsigned)cy < (unsigned)(T + 2) && (unsigned)cx < (unsigned)(T + 2)) {
            int cell = cy * (T + 2) + cx;
            int idx = atomicAdd(&scnt[cell], 1);
            if (idx < CAP) slist[cell * CAP + idx] = (unsigned short)r;
            else {
                int xi = atomicAdd(&sxcnt, 1);
                if (xi < XCAP) sextra[xi] = (unsigned)r | ((unsigned)cell << 12);
            }
        }
        if (g == 0) {
            bool owned = rx >= R && rx < R + T && ry >= R && ry < R + T;
            if (owned) {
                int dxo = x0 - sx, dyo = y0 - sy;
                if (dxo < -(R - 1) || dxo > R - 2 || dyo < -(R - 1) || dyo > R - 2) {
                    bool miss = false;
#pragma unroll
                    for (int ci = 0; ci < 2; ++ci)
#pragma unroll
                        for (int cj = 0; cj < 2; ++cj) {
                            int cxx = x0 + cj, cyy = y0 + ci;
                            if ((unsigned)cxx < (unsigned)W && (unsigned)cyy < (unsigned)H) {
                                int bx0 = (cxx / T) * T, by0 = (cyy / T) * T;
                                if (sx < bx0 - R || sx >= bx0 + T + R ||
                                    sy < by0 - R || sy >= by0 + T + R) miss = true;
                            }
                        }
                    if (miss) {
                        int ridx = atomicAdd(rec_cnt, 1);
                        if (ridx < rec_cap) rec_list[ridx] = (unsigned)(n * HW + sy * W + sx);
                    }
                }
            }
        }
    }

    // ---- staging writes (feature loads have been in flight across phase 1)
#pragma unroll
    for (int k = 0; k < KS; ++k) {
        int idx = tid + k * THREADS;
        if (idx < CB * RS) sfeat[idx] = fst[k];
    }
    __syncthreads();

    // ---- gather
    const int tgt = tid % TT;
    const int q = tid / TT;
    const int trow = tgt / T, tcol = tgt - trow * T;
    const int c0 = (trow + 1) * (T + 2) + (tcol + 1);
    const int c1 = c0 - 1;
    const int c2 = trow * (T + 2) + (tcol + 1);
    const int c3 = c2 - 1;
    const int n0 = scnt[c0] < CAP ? scnt[c0] : CAP;
    const int n1 = scnt[c1] < CAP ? scnt[c1] : CAP;
    const int n2 = scnt[c2] < CAP ? scnt[c2] : CAP;
    const int n3 = scnt[c3] < CAP ? scnt[c3] : CAP;
    const int xt = sxcnt < XCAP ? sxcnt : XCAP;
    const int cum0 = n0, cum1 = cum0 + n1, cum2 = cum1 + n2, tot = cum2 + n3;

    float acc[CPT];
#pragma unroll
    for (int u = 0; u < CPT; ++u) acc[u] = 0.f;
    float den = 0.f, wsm = 0.f;

    for (int i = 0; i < tot; ++i) {
        int j, kk, cell;
        if (i < cum0)      { j = 0; kk = i;        cell = c0; }
        else if (i < cum1) { j = 1; kk = i - cum0; cell = c1; }
        else if (i < cum2) { j = 2; kk = i - cum1; cell = c2; }
        else               { j = 3; kk = i - cum2; cell = c3; }
        int r = slist[cell * CAP + kk];
        float4 rc = srec[r];
        float wx = (j & 1) ? rc.y : 1.f - rc.y;
        float wy = (j & 2) ? rc.z : 1.f - rc.z;
        float bil = wx * wy;
        float w = rc.x * bil;
#pragma unroll
        for (int u = 0; u < CPT; ++u)
            acc[u] += w * sfeat[(q * CPT + u) * RS + r];
        den += w; wsm += bil;
    }
    for (int i = 0; i < xt; ++i) {
        unsigned pk = sextra[i];
        int r = pk & 0xFFF;
        int cell = (int)(pk >> 12);
        int j = (cell == c0) ? 0 : (cell == c1) ? 1 : (cell == c2) ? 2 : (cell == c3) ? 3 : -1;
        if (j >= 0) {
            float4 rc = srec[r];
            float wx = (j & 1) ? rc.y : 1.f - rc.y;
            float wy = (j & 2) ? rc.z : 1.f - rc.z;
            float bil = wx * wy;
            float w = rc.x * bil;
#pragma unroll
            for (int u = 0; u < CPT; ++u)
                acc[u] += w * sfeat[(q * CPT + u) * RS + r];
            den += w; wsm += bil;
        }
    }

    size_t tp = (size_t)(ty0 + trow) * W + tx0 + tcol;
#pragma unroll
    for (int u = 0; u < CPT; ++u)
        num[((size_t)n * C + g * CB + q * CPT + u) * HW + tp] = acc[u];
    if (g == 0 && q == 0)
        *(float2*)(dh + ((size_t)n * HW + tp) * 2) = make_float2(den, wsm);
}

// ---------------------------------------------------------------------------
// Flow-splat as a gather: per-source "features" are (dx*e, dy*e, e).
// Writes numF[tp*4 + {0,1,2}] with plain stores (slot 3 unused). Emits
// far-flow records -> splat_ffixup. No memset needed: every pixel is owned.
// ---------------------------------------------------------------------------
template <int H, int W, int T, int R, int THREADS>
__global__ __launch_bounds__(THREADS) void splat_fgather(
        const float* __restrict__ flow, float flow_scale, const float* __restrict__ metric,
        float* __restrict__ numF,
        int* __restrict__ rec_cnt, unsigned* __restrict__ rec_list, int rec_cap) {
    constexpr int HW = H * W;
    constexpr int RW = T + 2 * R;
    constexpr int RS = RW * RW;
    constexpr int GRIDC = (T + 2) * (T + 2);
    constexpr int CAP = 8;
    constexpr int XCAP = 256;
    constexpr int TT = T * T;
    static_assert(TT == THREADS, "one thread per target pixel");
    constexpr int TILES_X = W / T;
    constexpr int TILES = TILES_X * (H / T);
    constexpr int KCH = (RS + THREADS - 1) / THREADS;

    __shared__ float4 srec[RS];   // e, fx, fy, dx*e
    __shared__ float sdye[RS];    // dy*e
    __shared__ int scnt[GRIDC];
    __shared__ unsigned short slist[GRIDC * CAP];
    __shared__ unsigned sextra[XCAP];
    __shared__ int sxcnt;

    const int tid = threadIdx.x;
    int b = blockIdx.x;
    const int n = b / TILES;
    const int tt = b - n * TILES;
    const int ty0 = (tt / TILES_X) * T;
    const int tx0 = (tt - (tt / TILES_X) * TILES_X) * T;

    for (int i = tid; i < GRIDC; i += THREADS) scnt[i] = 0;
    if (tid == 0) sxcnt = 0;
    __syncthreads();

    const float* flowx = flow + (size_t)(n * 2 + 0) * HW;
    const float* flowy = flow + (size_t)(n * 2 + 1) * HW;
    const float* met = metric + (size_t)n * HW;

    float fdx[KCH], fdy[KCH], fme[KCH];
    bool val[KCH];
#pragma unroll
    for (int k = 0; k < KCH; ++k) {
        int r = tid + k * THREADS;
        int ry = r / RW, rx = r - ry * RW;
        int sy = ty0 - R + ry, sx = tx0 - R + rx;
        bool v = (r < RS) && ((unsigned)sx < (unsigned)W) && ((unsigned)sy < (unsigned)H);
        int sp = v ? sy * W + sx : 0;
        val[k] = v;
        fdx[k] = flowx[sp];
        fdy[k] = flowy[sp];
        fme[k] = met[sp];
    }

#pragma unroll
    for (int k = 0; k < KCH; ++k) {
        if (!val[k]) continue;
        int r = tid + k * THREADS;
        int ry = r / RW, rx = r - ry * RW;
        int sy = ty0 - R + ry, sx = tx0 - R + rx;
        float dx = fdx[k] * flow_scale;
        float dy = fdy[k] * flow_scale;
        float e = eweight(fme[k]);
        float gx = (float)sx + dx, gy = (float)sy + dy;
        float x0f = floorf(gx), y0f = floorf(gy);
        int x0 = (int)x0f, y0 = (int)y0f;
        srec[r] = make_float4(e, gx - x0f, gy - y0f, dx * e);
        sdye[r] = dy * e;
        int cy = y0 - ty0 + 1, cx = x0 - tx0 + 1;
        if ((unsigned)cy < (unsigned)(T + 2) && (unsigned)cx < (unsigned)(T + 2)) {
            int cell = cy * (T + 2) + cx;
            int idx = atomicAdd(&scnt[cell], 1);
            if (idx < CAP) slist[cell * CAP + idx] = (unsigned short)r;
            else {
                int xi = atomicAdd(&sxcnt, 1);
                if (xi < XCAP) sextra[xi] = (unsigned)r | ((unsigned)cell << 12);
            }
        }
        bool owned = rx >= R && rx < R + T && ry >= R && ry < R + T;
        if (owned) {
            int dxo = x0 - sx, dyo = y0 - sy;
            if (dxo < -(R - 1) || dxo > R - 2 || dyo < -(R - 1) || dyo > R - 2) {
                bool miss = false;
#pragma unroll
                for (int ci = 0; ci < 2; ++ci)
#pragma unroll
                    for (int cj = 0; cj < 2; ++cj) {
                        int cxx = x0 + cj, cyy = y0 + ci;
                        if ((unsigned)cxx < (unsigned)W && (unsigned)cyy < (unsigned)H) {
                            int bx0 = (cxx / T) * T, by0 = (cyy / T) * T;
                            if (sx < bx0 - R || sx >= bx0 + T + R ||
                                sy < by0 - R || sy >= by0 + T + R) miss = true;
                        }
                    }
                if (miss) {
                    int ridx = atomicAdd(rec_cnt, 1);
                    if (ridx < rec_cap) rec_list[ridx] = (unsigned)(n * HW + sy * W + sx);
                }
            }
        }
    }
    __syncthreads();

    const int trow = tid / T, tcol = tid - trow * T;
    const int c0 = (trow + 1) * (T + 2) + (tcol + 1);
    const int c1 = c0 - 1;
    const int c2 = trow * (T + 2) + (tcol + 1);
    const int c3 = c2 - 1;
    const int n0 = scnt[c0] < CAP ? scnt[c0] : CAP;
    const int n1 = scnt[c1] < CAP ? scnt[c1] : CAP;
    const int n2 = scnt[c2] < CAP ? scnt[c2] : CAP;
    const int n3 = scnt[c3] < CAP ? scnt[c3] : CAP;
    const int xt = sxcnt < XCAP ? sxcnt : XCAP;
    const int cum0 = n0, cum1 = cum0 + n1, cum2 = cum1 + n2, tot = cum2 + n3;

    float a0 = 0.f, a1 = 0.f, a2 = 0.f;
    for (int i = 0; i < tot; ++i) {
        int j, kk, cell;
        if (i < cum0)      { j = 0; kk = i;        cell = c0; }
        else if (i < cum1) { j = 1; kk = i - cum0; cell = c1; }
        else if (i < cum2) { j = 2; kk = i - cum1; cell = c2; }
        else               { j = 3; kk = i - cum2; cell = c3; }
        int r = slist[cell * CAP + kk];
        float4 rc = srec[r];
        float wx = (j & 1) ? rc.y : 1.f - rc.y;
        float wy = (j & 2) ? rc.z : 1.f - rc.z;
        float bil = wx * wy;
        a0 += bil * rc.w;
        a1 += bil * sdye[r];
        a2 += bil * rc.x;
    }
    for (int i = 0; i < xt; ++i) {
        unsigned pk = sextra[i];
        int r = pk & 0xFFF;
        int cell = (int)(pk >> 12);
        int j = (cell == c0) ? 0 : (cell == c1) ? 1 : (cell == c2) ? 2 : (cell == c3) ? 3 : -1;
        if (j >= 0) {
            float4 rc = srec[r];
            float wx = (j & 1) ? rc.y : 1.f - rc.y;
            float wy = (j & 2) ? rc.z : 1.f - rc.z;
            float bil = wx * wy;
            a0 += bil * rc.w;
            a1 += bil * sdye[r];
            a2 += bil * rc.x;
        }
    }

    size_t base = ((size_t)n * HW + (size_t)(ty0 + trow) * W + tx0 + tcol) * 4;
    *(float2*)(numF + base) = make_float2(a0, a1);
    numF[base + 2] = a2;
}

// ---------------------------------------------------------------------------
// Far-flow fixups (rare): features version (as R4, proven) + flow version.
// ---------------------------------------------------------------------------
template <int C, int H, int W, int T, int R>
__global__ __launch_bounds__(128) void splat_fixup(
        const float* __restrict__ feat, const float* __restrict__ flow, float flow_scale,
        const float* __restrict__ metric, float* __restrict__ num, float* __restrict__ dh,
        const int* __restrict__ rec_cnt, const unsigned* __restrict__ rec_list, int rec_cap) {
    constexpr int HW = H * W;
    int cnt = *rec_cnt;
    if (cnt > rec_cap) cnt = rec_cap;
    for (int rec = blockIdx.x; rec < cnt; rec += gridDim.x) {
        unsigned qv = rec_list[rec];
        int n = qv / HW;
        int p = qv - n * HW;
        int sy = p / W;
        int sx = p - sy * W;
        float dx = flow[(size_t)(n * 2 + 0) * HW + p] * flow_scale;
        float dy = flow[(size_t)(n * 2 + 1) * HW + p] * flow_scale;
        float e = eweight(metric[(size_t)n * HW + p]);
        float gx = (float)sx + dx, gy = (float)sy + dy;
        float x0f = floorf(gx), y0f = floorf(gy);
        float fx = gx - x0f, fy = gy - y0f;
        int x0 = (int)x0f, y0 = (int)y0f;
        float wxs[2] = { 1.f - fx, fx }, wys[2] = { 1.f - fy, fy };
        for (int idx = threadIdx.x; idx < 4 * C; idx += 128) {
            int corner = idx / C;
            int c = idx - corner * C;
            int ci = corner >> 1, cj = corner & 1;
            int cx = x0 + cj, cy = y0 + ci;
            if ((unsigned)cx >= (unsigned)W || (unsigned)cy >= (unsigned)H) continue;
            int bx0 = (cx / T) * T, by0 = (cy / T) * T;
            bool miss = sx < bx0 - R || sx >= bx0 + T + R ||
                        sy < by0 - R || sy >= by0 + T + R;
            if (!miss) continue;
            float w = wxs[cj] * wys[ci];
            atomicAdd(&num[((size_t)n * C + c) * HW + (size_t)cy * W + cx],
                      feat[((size_t)n * C + c) * HW + p] * (e * w));
            if (c == 0) {
                size_t tp = ((size_t)n * H + cy) * W + cx;
                atomicAdd(&dh[tp * 2], e * w);
                atomicAdd(&dh[tp * 2 + 1], w);
            }
        }
    }
}

template <int H, int W, int T, int R>
__global__ __launch_bounds__(256) void splat_ffixup(
        const float* __restrict__ flow, float flow_scale, const float* __restrict__ metric,
        float* __restrict__ numF,
        const int* __restrict__ rec_cnt, const unsigned* __restrict__ rec_list, int rec_cap) {
    constexpr int HW = H * W;
    int cnt = *rec_cnt;
    if (cnt > rec_cap) cnt = rec_cap;
    int stride = gridDim.x * blockDim.x;
    for (int i = blockIdx.x * blockDim.x + threadIdx.x; i < cnt * 4; i += stride) {
        int rec = i >> 2, corner = i & 3;
        unsigned qv = rec_list[rec];
        int n = qv / HW;
        int p = qv - n * HW;
        int sy = p / W;
        int sx = p - sy * W;
        float dx = flow[(size_t)(n * 2 + 0) * HW + p] * flow_scale;
        float dy = flow[(size_t)(n * 2 + 1) * HW + p] * flow_scale;
        float e = eweight(metric[(size_t)n * HW + p]);
        float gx = (float)sx + dx, gy = (float)sy + dy;
        float x0f = floorf(gx), y0f = floorf(gy);
        float fx = gx - x0f, fy = gy - y0f;
        int x0 = (int)x0f, y0 = (int)y0f;
        int cj = corner & 1, ci = corner >> 1;
        int cx = x0 + cj, cy = y0 + ci;
        if ((unsigned)cx >= (unsigned)W || (unsigned)cy >= (unsigned)H) continue;
        int bx0 = (cx / T) * T, by0 = (cy / T) * T;
        bool miss = sx < bx0 - R || sx >= bx0 + T + R ||
                    sy < by0 - R || sy >= by0 + T + R;
        if (!miss) continue;
        float w = ((cj) ? fx : 1.f - fx) * ((ci) ? fy : 1.f - fy);
        size_t base = ((size_t)n * HW + (size_t)cy * W + cx) * 4;
        atomicAdd(&numF[base + 0], w * dx * e);
        atomicAdd(&numF[base + 1], w * dy * e);
        atomicAdd(&numF[base + 2], w * e);
    }
}

// ---------------------------------------------------------------------------
// NCHW normalize + hole mask (c==0 lanes). float4-vectorized.
// ---------------------------------------------------------------------------
template <int C, int H, int W>
__global__ __launch_bounds__(256) void norm_nchw(const float* __restrict__ num,
                                                 const float* __restrict__ dh,
                                                 float* __restrict__ out,
                                                 float* __restrict__ hole) {
    constexpr int HW = H * W;
    constexpr int N = 4;
    int q4 = blockIdx.x * 256 + threadIdx.x;
    if (q4 >= N * C * HW / 4) return;
    int idx = q4 * 4;
    int per = C * HW;
    int n = idx / per;
    int rem = idx - n * per;
    int c = rem / HW;
    int p = rem - c * HW;
    float4 v = *(const float4*)(num + idx);
    const float2* dp = (const float2*)(dh + ((size_t)n * HW + p) * 2);
    float2 d0 = dp[0], d1 = dp[1], d2 = dp[2], d3 = dp[3];
    float4 o;
    o.x = v.x / (d0.x + EPS);
    o.y = v.y / (d1.x + EPS);
    o.z = v.z / (d2.x + EPS);
    o.w = v.w / (d3.x + EPS);
    *(float4*)(out + idx) = o;
    if (c == 0) {
        float4 hm;
        hm.x = (d0.y / (d0.y + EPS) <= 0.5f) ? 1.f : 0.f;
        hm.y = (d1.y / (d1.y + EPS) <= 0.5f) ? 1.f : 0.f;
        hm.z = (d2.y / (d2.y + EPS) <= 0.5f) ? 1.f : 0.f;
        hm.w = (d3.y / (d3.y + EPS) <= 0.5f) ? 1.f : 0.f;
        *(float4*)(hole + (size_t)n * HW + p) = hm;
    }
}

__global__ __launch_bounds__(256) void norm_flow(const float* __restrict__ num,
                                                 float* __restrict__ out, int HW, int total) {
    int q = blockIdx.x * blockDim.x + threadIdx.x;
    if (q >= total) return;
    float4 v = ((const float4*)num)[q];
    int n = q / HW;
    int p = q - n * HW;
    float inv = -1.0f / (v.z + EPS);
    out[((size_t)n * 2 + 0) * HW + p] = v.x * inv;
    out[((size_t)n * 2 + 1) * HW + p] = v.y * inv;
}

// ---------------------------------------------------------------------------
extern "C" void kernel_launch(void* const* d_in, const int* in_sizes, int n_in,
                              void* d_out, int out_size, void* d_ws, size_t ws_size,
                              hipStream_t stream) {
    const float* x1_0 = (const float*)d_in[0];
    const float* x1_1 = (const float*)d_in[2];
    const float* x1_2 = (const float*)d_in[4];
    const float* m1t  = (const float*)d_in[6];
    const float* m2t  = (const float*)d_in[7];
    const float* F12  = (const float*)d_in[8];
    const float* F21  = (const float*)d_in[9];

    const int N = 4;
    const int H0 = 256, W0 = 448;
    const int H1 = 128, W1 = 224;
    const int H2 = 64,  W2 = 112;
    const int HW0 = H0 * W0, HW1 = H1 * W1, HW2 = H2 * W2;
    const int NHW0 = N * HW0, NHW1 = N * HW1, NHW2 = N * HW2;

    // d_out layout (floats), reference return order
    const size_t o0 = 0;
    const size_t o1 = o0 + (size_t)N * 32 * HW0;
    const size_t o2 = o1 + (size_t)N * 64 * HW1;
    const size_t o3 = o2 + (size_t)N * 96 * HW2;
    const size_t o4 = o3 + (size_t)NHW0;
    const size_t o5 = o4 + (size_t)NHW1;
    const size_t o6 = o5 + (size_t)NHW2;
    float* out = (float*)d_out;

    // ws layout: [numF | cnts(zeroed) | rec lists | pyramid | num/dh buffers]
    float* ws_f = (float*)d_ws;
    float* numF = ws_f;                                   // NHW0*4 (fully written by fgather)
    int* cnts = (int*)(numF + (size_t)NHW0 * 4);          // 4 ints, zeroed
    unsigned* list0 = (unsigned*)(cnts + 4);              // 32768
    unsigned* list1 = list0 + 32768;                      // 2048
    unsigned* list2 = list1 + 2048;                       // 2048
    unsigned* list3 = list2 + 2048;                       // 32768
    float* flow1   = (float*)(list3 + 32768);             // 2*NHW1
    float* metric1 = flow1 + (size_t)2 * NHW1;            // NHW1
    float* flow2   = metric1 + NHW1;                      // 2*NHW2
    float* metric2 = flow2 + (size_t)2 * NHW2;            // NHW2
    float* num0 = metric2 + NHW2;                         // N*32*HW0
    float* dh0  = num0 + (size_t)N * 32 * HW0;            // NHW0*2
    float* num1 = dh0 + (size_t)NHW0 * 2;                 // N*64*HW1
    float* dh1  = num1 + (size_t)N * 64 * HW1;            // NHW1*2
    float* num2 = dh1 + (size_t)NHW1 * 2;                 // N*96*HW2
    float* dh2  = num2 + (size_t)N * 96 * HW2;            // NHW2*2

    hipMemsetAsync(cnts, 0, 4 * sizeof(int), stream);

    const int B = 256;

    // pyramid resizes (flow scale folded: F1t = 0.5*F12)
    downsample2_kernel<<<cdiv_i(N * 1 * HW1, B), B, 0, stream>>>(m1t, metric1, N, H0, W0, 1.0f);
    downsample2_kernel<<<cdiv_i(N * 2 * HW1, B), B, 0, stream>>>(F12, flow1, N * 2, H0, W0, 0.25f);
    downsample2_kernel<<<cdiv_i(N * 1 * HW2, B), B, 0, stream>>>(metric1, metric2, N, H1, W1, 1.0f);
    downsample2_kernel<<<cdiv_i(N * 2 * HW2, B), B, 0, stream>>>(flow1, flow2, N * 2, H1, W1, 0.5f);

    // channel-split bucketed-gather splats
    // L0: 1792 tiles x 8 groups = 14336 blocks of 512
    splat_gather2<32, 256, 448, 16, 12, 4, 512><<<14336, 512, 0, stream>>>(
        x1_0, F12, 0.5f, m1t, num0, dh0, cnts + 0, list0, 32768);
    // L1: 448 tiles x 4 groups = 1792 blocks of 512
    splat_gather2<64, 128, 224, 16, 4, 16, 512><<<1792, 512, 0, stream>>>(
        x1_1, flow1, 1.0f, metric1, num1, dh1, cnts + 1, list1, 2048);
    // L2: 448 tiles x 3 groups = 1344 blocks of 256
    splat_gather2<96, 64, 112, 8, 4, 32, 256><<<1344, 256, 0, stream>>>(
        x1_2, flow2, 1.0f, metric2, num2, dh2, cnts + 2, list2, 2048);
    // flow: 1792 tile blocks of 256 (gather; replaces atomic splat_flow)
    splat_fgather<256, 448, 16, 12, 256><<<1792, 256, 0, stream>>>(
        F21, 0.5f, m2t, numF, cnts + 3, list3, 32768);

    // rare far-flow fixups (before normalization)
    splat_fixup<32, 256, 448, 16, 12><<<2048, 128, 0, stream>>>(
        x1_0, F12, 0.5f, m1t, num0, dh0, cnts + 0, list0, 32768);
    splat_fixup<64, 128, 224, 16, 4><<<256, 128, 0, stream>>>(
        x1_1, flow1, 1.0f, metric1, num1, dh1, cnts + 1, list1, 2048);
    splat_fixup<96, 64, 112, 8, 4><<<256, 128, 0, stream>>>(
        x1_2, flow2, 1.0f, metric2, num2, dh2, cnts + 2, list2, 2048);
    splat_ffixup<256, 448, 16, 12><<<256, 256, 0, stream>>>(
        F21, 0.5f, m2t, numF, cnts + 3, list3, 32768);

    // normalize (NCHW) + hole masks
    norm_nchw<32, 256, 448><<<cdiv_i(N * 32 * HW0 / 4, B), B, 0, stream>>>(num0, dh0, out + o0, out + o3);
    norm_nchw<64, 128, 224><<<cdiv_i(N * 64 * HW1 / 4, B), B, 0, stream>>>(num1, dh1, out + o1, out + o4);
    norm_nchw<96, 64, 112><<<cdiv_i(N * 96 * HW2 / 4, B), B, 0, stream>>>(num2, dh2, out + o2, out + o5);
    norm_flow<<<cdiv_i(NHW0, B), B, 0, stream>>>(numF, out + o6, HW0, NHW0);
}